// Round 13
// baseline (685.254 us; speedup 1.0000x reference)
//
#include <hip/hip_runtime.h>
#include <cstdint>
#include <cstddef>

constexpr int kN   = 50000;          // nodes
constexpr int kE   = 800000;         // edges (without self loops)
constexpr int kEt  = kE + kN;        // edges + self loops
constexpr float kSlope = 0.2f;       // leaky relu slope

typedef __attribute__((ext_vector_type(8))) short bf8_t;   // 8 bf16 = 4 VGPRs
typedef __attribute__((ext_vector_type(4))) float f4_t;

// ---------------- static device workspace (d_ws unused) ---------------------
__device__ __align__(16) unsigned short g_aggx_h[(size_t)kN * 512]; // agg of x, bf16 hi
__device__ __align__(16) unsigned short g_aggx_l[(size_t)kN * 512]; // bf16 lo residual
__device__ __align__(16) unsigned g_h1p[(size_t)kN * 512];          // h1 packed hi|lo
__device__ __align__(16) unsigned short g_w1t_h[4 * 128 * 128];     // W1^T per head, hi
__device__ __align__(16) unsigned short g_w1t_l[4 * 128 * 128];
__device__ __align__(16) unsigned short g_w2t_h[128 * 512];         // W2^T, hi
__device__ __align__(16) unsigned short g_w2t_l[128 * 512];
__device__ __align__(16) float g_h2  [(size_t)kN * 128];  // layer-2 pre-agg features
__device__ __align__(16) float g_h2p [2][(size_t)kN * 128]; // split-K partials
__device__ __align__(16) float g_es1[kN * 4];
__device__ __align__(16) float g_ed1[kN * 4];
__device__ float g_es2[kN];
__device__ float g_ed2[kN];
__device__ __align__(16) float g_p1s[4 * 128];  // folded W1_h @ a1_src_h
__device__ __align__(16) float g_p1d[4 * 128];
// CSR by destination:
__device__ int g_deg[kN];
__device__ int g_ptr[kN + 1];
__device__ int g_cur[kN];
__device__ int g_srcs[kEt];

__device__ __forceinline__ float lrelu(float x) { return x > 0.f ? x : kSlope * x; }

__device__ __forceinline__ bf8_t bf8_zero() {
  uint4 z = make_uint4(0u, 0u, 0u, 0u);
  return *(bf8_t*)&z;
}

// round-to-nearest-even f32 -> bf16
__device__ __forceinline__ unsigned short f2bf(float v, float& hi_f) {
  unsigned u = __float_as_uint(v);
  unsigned r = (u + 0x7FFFu + ((u >> 16) & 1u)) & 0xFFFF0000u;
  hi_f = __uint_as_float(r);
  return (unsigned short)(r >> 16);
}
__device__ __forceinline__ void split_bf(float v, unsigned short& h, unsigned short& l) {
  float hf, lf;
  h = f2bf(v, hf);
  l = f2bf(v - hf, lf);
}

// unpack 8 packed (hi<<16|lo) u32 -> hi bf8 + lo bf8
__device__ __forceinline__ void unpack8(uint4 u0, uint4 u1, bf8_t& h, bf8_t& l) {
  unsigned uu[8] = {u0.x, u0.y, u0.z, u0.w, u1.x, u1.y, u1.z, u1.w};
  unsigned hp[4], lp[4];
#pragma unroll
  for (int i = 0; i < 4; ++i) {
    hp[i] = (uu[2 * i] >> 16) | (uu[2 * i + 1] & 0xFFFF0000u);
    lp[i] = (uu[2 * i] & 0xFFFFu) | (uu[2 * i + 1] << 16);
  }
  uint4 hv = make_uint4(hp[0], hp[1], hp[2], hp[3]);
  uint4 lv = make_uint4(lp[0], lp[1], lp[2], lp[3]);
  h = *(bf8_t*)&hv;
  l = *(bf8_t*)&lv;
}

// ------- merged init: zero_deg (blocks 0..196) | convw (197..708) | prep1 ---
__global__ __launch_bounds__(256) void k_init(const float* __restrict__ W1,
    const float* __restrict__ W2, const float* __restrict__ a1s,
    const float* __restrict__ a1d) {
  const int b = blockIdx.x, t = threadIdx.x;
  if (b < 197) {
    int i = b * 256 + t;
    if (i < kN) g_deg[i] = 0;
  } else if (b < 709) {
    int gid = (b - 197) * 256 + t;   // 0..131071
    if (gid < 65536) {
      int h = gid >> 14, rem = gid & 16383;
      int c = rem >> 7, j = rem & 127;
      float v = W1[(size_t)c * 512 + h * 128 + j];
      unsigned short hh, ll;
      split_bf(v, hh, ll);
      size_t o = ((size_t)h * 128 + j) * 128 + c;
      g_w1t_h[o] = hh; g_w1t_l[o] = ll;
    } else {
      int g2 = gid - 65536;
      int k = g2 >> 7, j = g2 & 127;
      float v = W2[(size_t)k * 128 + j];
      unsigned short hh, ll;
      split_bf(v, hh, ll);
      size_t o = (size_t)j * 512 + k;
      g_w2t_h[o] = hh; g_w2t_l[o] = ll;
    }
  } else {
    int gid = (b - 709) * 256 + t;   // 0..1023
    int which = gid >> 9, idx = gid & 511;
    int h = idx >> 7, k = idx & 127;
    const float* a = which ? a1d : a1s;
    const float* wrow = W1 + (size_t)k * 512 + h * 128;
    float s = 0.f;
#pragma unroll 8
    for (int c = 0; c < 128; ++c) s += wrow[c] * a[h * 128 + c];
    (which ? g_p1d : g_p1s)[idx] = s;
  }
}

__global__ __launch_bounds__(256) void k_hist(const int* __restrict__ ei) {
  int e = blockIdx.x * 256 + threadIdx.x;
  if (e >= kEt) return;
  int d = (e < kE) ? ei[kE + e] : e - kE;
  atomicAdd(&g_deg[d], 1);
}

__global__ __launch_bounds__(1024) void k_scan() {
  __shared__ int s_sum[1024];
  const int t = threadIdx.x;
  const int chunk = (kN + 1023) / 1024;        // 49
  const int lo = t * chunk, hi = min(lo + chunk, kN);
  int sum = 0;
  for (int i = lo; i < hi; ++i) sum += g_deg[i];
  s_sum[t] = sum;
  __syncthreads();
  for (int off = 1; off < 1024; off <<= 1) {
    int xv = s_sum[t];
    int yv = (t >= off) ? s_sum[t - off] : 0;
    __syncthreads();
    s_sum[t] = xv + yv;
    __syncthreads();
  }
  int run = s_sum[t] - sum;
  for (int i = lo; i < hi; ++i) {
    g_ptr[i] = run;
    g_cur[i] = run;
    run += g_deg[i];
  }
  if (t == 1023) g_ptr[kN] = run;
}

__global__ __launch_bounds__(256) void k_scatter(const int* __restrict__ ei) {
  int e = blockIdx.x * 256 + threadIdx.x;
  if (e >= kEt) return;
  int s, d;
  if (e < kE) { s = ei[e]; d = ei[kE + e]; } else { s = d = e - kE; }
  int slot = atomicAdd(&g_cur[d], 1);
  g_srcs[slot] = s;
}

// ---- layer-1 scores directly from x ----
__global__ __launch_bounds__(256) void k_scores1x(const float* __restrict__ x) {
  const int lane = threadIdx.x & 63;
  const int n = (blockIdx.x * 256 + threadIdx.x) >> 6;
  if (n >= kN) return;
  float x0 = x[(size_t)n * 128 + lane];
  float x1 = x[(size_t)n * 128 + 64 + lane];
  float s[4], d[4];
#pragma unroll
  for (int h = 0; h < 4; ++h) {
    s[h] = x0 * g_p1s[h * 128 + lane] + x1 * g_p1s[h * 128 + 64 + lane];
    d[h] = x0 * g_p1d[h * 128 + lane] + x1 * g_p1d[h * 128 + 64 + lane];
  }
#pragma unroll
  for (int off = 32; off > 0; off >>= 1) {
#pragma unroll
    for (int h = 0; h < 4; ++h) {
      s[h] += __shfl_down(s[h], off);
      d[h] += __shfl_down(d[h], off);
    }
  }
  if (lane == 0) {
    *(float4*)(g_es1 + (size_t)n * 4) = make_float4(s[0], s[1], s[2], s[3]);
    *(float4*)(g_ed1 + (size_t)n * 4) = make_float4(d[0], d[1], d[2], d[3]);
  }
}

// ---- layer-1 aggregation: 4 edges/iter (16-lane quarters), 2xfloat4/lane ---
__global__ __launch_bounds__(256) void k_agg1x(const float* __restrict__ x) {
  const int lane = threadIdx.x & 63;
  const int n = (blockIdx.x * 256 + threadIdx.x) >> 6;
  if (n >= kN) return;
  const int beg = g_ptr[n], end = g_ptr[n + 1];
  const float4 ed = *(const float4*)(g_ed1 + (size_t)n * 4);
  const int qt = lane >> 4, ql = lane & 15;
  float z0 = 0.f, z1 = 0.f, z2 = 0.f, z3 = 0.f;
  float acc[4][8] = {};
  for (int base = beg; base < end; base += 64) {
    const int cnt = min(64, end - base);
    int s = 0;
    float w0 = 0.f, w1 = 0.f, w2 = 0.f, w3 = 0.f;
    if (lane < cnt) {
      s = g_srcs[base + lane];
      float4 es = *(const float4*)(g_es1 + (size_t)s * 4);
      w0 = __expf(lrelu(es.x + ed.x));
      w1 = __expf(lrelu(es.y + ed.y));
      w2 = __expf(lrelu(es.z + ed.z));
      w3 = __expf(lrelu(es.w + ed.w));
      z0 += w0; z1 += w1; z2 += w2; z3 += w3;
    }
    const int quads = (cnt + 3) >> 2;
#pragma unroll 2
    for (int p = 0; p < quads; ++p) {
      int ei = 4 * p + qt;
      int   sj = __shfl(s, ei);
      float b0 = __shfl(w0, ei), b1 = __shfl(w1, ei);
      float b2 = __shfl(w2, ei), b3 = __shfl(w3, ei);
      const float* xp = x + (size_t)sj * 128 + ql * 8;
      float4 f0 = *(const float4*)xp;
      float4 f1 = *(const float4*)(xp + 4);
      float fv[8] = {f0.x, f0.y, f0.z, f0.w, f1.x, f1.y, f1.z, f1.w};
#pragma unroll
      for (int k = 0; k < 8; ++k) {
        acc[0][k] += b0 * fv[k];
        acc[1][k] += b1 * fv[k];
        acc[2][k] += b2 * fv[k];
        acc[3][k] += b3 * fv[k];
      }
    }
  }
#pragma unroll
  for (int h = 0; h < 4; ++h)
#pragma unroll
    for (int k = 0; k < 8; ++k) {
      acc[h][k] += __shfl_xor(acc[h][k], 16);
      acc[h][k] += __shfl_xor(acc[h][k], 32);
    }
#pragma unroll
  for (int off = 1; off < 64; off <<= 1) {
    z0 += __shfl_xor(z0, off); z1 += __shfl_xor(z1, off);
    z2 += __shfl_xor(z2, off); z3 += __shfl_xor(z3, off);
  }
  float zh = qt == 0 ? z0 : qt == 1 ? z1 : qt == 2 ? z2 : z3;
  float iz = 1.f / zh;
  float v[8];
#pragma unroll
  for (int k = 0; k < 8; ++k)
    v[k] = (qt == 0 ? acc[0][k] : qt == 1 ? acc[1][k] : qt == 2 ? acc[2][k] : acc[3][k]) * iz;
  ushort4 h0, l0, h1, l1;
  split_bf(v[0], h0.x, l0.x); split_bf(v[1], h0.y, l0.y);
  split_bf(v[2], h0.z, l0.z); split_bf(v[3], h0.w, l0.w);
  split_bf(v[4], h1.x, l1.x); split_bf(v[5], h1.y, l1.y);
  split_bf(v[6], h1.z, l1.z); split_bf(v[7], h1.w, l1.w);
  size_t o = (size_t)n * 512 + qt * 128 + ql * 8;
  *(ushort4*)(g_aggx_h + o) = h0; *(ushort4*)(g_aggx_h + o + 4) = h1;
  *(ushort4*)(g_aggx_l + o) = l0; *(ushort4*)(g_aggx_l + o + 4) = l1;
}

// ------- layer-1 expand: barrier-free, no LDS -------------------------------
// 64-row x 1-head blocks (grid 782 x 4 = 3128). Direct-load fragments; output
// h1 packed (hi<<16|lo) to g_h1p, fully independent waves.
__global__ __launch_bounds__(256) void k_exp(const float* __restrict__ b1) {
  const int t = threadIdx.x;
  const int lane = t & 63, w = t >> 6;
  const int wrow = w >> 1, wcol = w & 1;
  const int ln15 = lane & 15, q = lane >> 4, qo = q * 8;
  const int row0 = blockIdx.y * 64;
  const int h = blockIdx.z;
  f4_t acc[2][4] = {};
#pragma unroll
  for (int ks = 0; ks < 128; ks += 32) {
    bf8_t ah[2], al[2];
#pragma unroll
    for (int i = 0; i < 2; ++i) {
      int r = row0 + wrow * 32 + i * 16 + ln15;
      ah[i] = bf8_zero(); al[i] = bf8_zero();
      if (r < kN) {
        size_t ga = (size_t)r * 512 + h * 128 + ks + qo;
        ah[i] = *(const bf8_t*)&g_aggx_h[ga];
        al[i] = *(const bf8_t*)&g_aggx_l[ga];
      }
    }
#pragma unroll
    for (int j = 0; j < 4; ++j) {
      size_t gb = ((size_t)h * 128 + wcol * 64 + j * 16 + ln15) * 128 + ks + qo;
      bf8_t bh = *(const bf8_t*)&g_w1t_h[gb];
      bf8_t bl = *(const bf8_t*)&g_w1t_l[gb];
#pragma unroll
      for (int i = 0; i < 2; ++i)
        acc[i][j] = __builtin_amdgcn_mfma_f32_16x16x32_bf16(ah[i], bh, acc[i][j], 0, 0, 0);
#pragma unroll
      for (int i = 0; i < 2; ++i)
        acc[i][j] = __builtin_amdgcn_mfma_f32_16x16x32_bf16(al[i], bh, acc[i][j], 0, 0, 0);
#pragma unroll
      for (int i = 0; i < 2; ++i)
        acc[i][j] = __builtin_amdgcn_mfma_f32_16x16x32_bf16(ah[i], bl, acc[i][j], 0, 0, 0);
    }
  }
  // epilogue: bias + relu + split + packed store
#pragma unroll
  for (int j = 0; j < 4; ++j) {
    int col = wcol * 64 + j * 16 + ln15;
    float bv = b1[h * 128 + col];
#pragma unroll
    for (int i = 0; i < 2; ++i)
#pragma unroll
      for (int reg = 0; reg < 4; ++reg) {
        int r = row0 + wrow * 32 + i * 16 + q * 4 + reg;
        if (r < kN) {
          float v = fmaxf(acc[i][j][reg] + bv, 0.f);
          unsigned short hb, lb;
          split_bf(v, hb, lb);
          g_h1p[(size_t)r * 512 + h * 128 + col] = ((unsigned)hb << 16) | lb;
        }
      }
  }
}

// ------- layer-2 GEMM: barrier-free, no LDS, split-K=2 ----------------------
// 64-row blocks x 2 K-slices (grid 782 x 2 = 1564). A unpacked from g_h1p.
__global__ __launch_bounds__(256) void k_gemm2() {
  const int t = threadIdx.x;
  const int lane = t & 63, w = t >> 6;
  const int wrow = w >> 1, wcol = w & 1;
  const int ln15 = lane & 15, q = lane >> 4, qo = q * 8;
  const int row0 = blockIdx.y * 64;
  const int z = blockIdx.z;
  f4_t acc[2][4] = {};
#pragma unroll 2
  for (int ks = 0; ks < 256; ks += 32) {
    bf8_t ah[2], al[2];
#pragma unroll
    for (int i = 0; i < 2; ++i) {
      int r = row0 + wrow * 32 + i * 16 + ln15;
      uint4 u0 = make_uint4(0u, 0u, 0u, 0u), u1 = u0;
      if (r < kN) {
        const unsigned* p = g_h1p + (size_t)r * 512 + z * 256 + ks + qo;
        u0 = *(const uint4*)p;
        u1 = *(const uint4*)(p + 4);
      }
      unpack8(u0, u1, ah[i], al[i]);
    }
#pragma unroll
    for (int j = 0; j < 4; ++j) {
      size_t gb = (size_t)(wcol * 64 + j * 16 + ln15) * 512 + z * 256 + ks + qo;
      bf8_t bh = *(const bf8_t*)&g_w2t_h[gb];
      bf8_t bl = *(const bf8_t*)&g_w2t_l[gb];
#pragma unroll
      for (int i = 0; i < 2; ++i)
        acc[i][j] = __builtin_amdgcn_mfma_f32_16x16x32_bf16(ah[i], bh, acc[i][j], 0, 0, 0);
#pragma unroll
      for (int i = 0; i < 2; ++i)
        acc[i][j] = __builtin_amdgcn_mfma_f32_16x16x32_bf16(al[i], bh, acc[i][j], 0, 0, 0);
#pragma unroll
      for (int i = 0; i < 2; ++i)
        acc[i][j] = __builtin_amdgcn_mfma_f32_16x16x32_bf16(ah[i], bl, acc[i][j], 0, 0, 0);
    }
  }
  float* outp = g_h2p[z];
#pragma unroll
  for (int j = 0; j < 4; ++j) {
    int col = wcol * 64 + j * 16 + ln15;
#pragma unroll
    for (int i = 0; i < 2; ++i)
#pragma unroll
      for (int reg = 0; reg < 4; ++reg) {
        int r = row0 + wrow * 32 + i * 16 + q * 4 + reg;
        if (r < kN) outp[(size_t)r * 128 + col] = acc[i][j][reg];
      }
  }
}

// ---- fused partial-sum (2 slices) + layer-2 scores; materializes g_h2 ----
__global__ __launch_bounds__(256) void k_scores2(const float* __restrict__ asrc,
                                                 const float* __restrict__ adst) {
  const int lane = threadIdx.x & 63;
  const int n = (blockIdx.x * 256 + threadIdx.x) >> 6;
  if (n >= kN) return;
  const size_t o = (size_t)n * 128;
  float v0 = g_h2p[0][o + lane]      + g_h2p[1][o + lane];
  float v1 = g_h2p[0][o + 64 + lane] + g_h2p[1][o + 64 + lane];
  g_h2[o + lane] = v0;
  g_h2[o + 64 + lane] = v1;
  float s = v0 * asrc[lane] + v1 * asrc[64 + lane];
  float d = v0 * adst[lane] + v1 * adst[64 + lane];
#pragma unroll
  for (int off = 32; off > 0; off >>= 1) {
    s += __shfl_down(s, off);
    d += __shfl_down(d, off);
  }
  if (lane == 0) { g_es2[n] = s; g_ed2[n] = d; }
}

// ---- layer-2 aggregation: 4 edges/iter (quarters) + fused FC ---------------
__global__ __launch_bounds__(256) void k_agg2x(const float* __restrict__ b2,
    const float* __restrict__ fcw, const float* __restrict__ fcb,
    float* __restrict__ out) {
  const int lane = threadIdx.x & 63;
  const int n = (blockIdx.x * 256 + threadIdx.x) >> 6;
  if (n >= kN) return;
  const int beg = g_ptr[n], end = g_ptr[n + 1];
  const float ed = g_ed2[n];
  const int qt = lane >> 4, ql = lane & 15;
  float zp = 0.f;
  float acc[8] = {};
  for (int base = beg; base < end; base += 64) {
    const int cnt = min(64, end - base);
    int s = 0; float w = 0.f;
    if (lane < cnt) {
      s = g_srcs[base + lane];
      w = __expf(lrelu(g_es2[s] + ed));
      zp += w;
    }
    const int quads = (cnt + 3) >> 2;
#pragma unroll 2
    for (int p = 0; p < quads; ++p) {
      int ei = 4 * p + qt;
      int   sj = __shfl(s, ei);
      float wj = __shfl(w, ei);
      const float* hp = g_h2 + (size_t)sj * 128 + ql * 8;
      float4 f0 = *(const float4*)hp;
      float4 f1 = *(const float4*)(hp + 4);
      acc[0] += wj * f0.x; acc[1] += wj * f0.y;
      acc[2] += wj * f0.z; acc[3] += wj * f0.w;
      acc[4] += wj * f1.x; acc[5] += wj * f1.y;
      acc[6] += wj * f1.z; acc[7] += wj * f1.w;
    }
  }
#pragma unroll
  for (int off = 1; off < 64; off <<= 1) zp += __shfl_xor(zp, off);
#pragma unroll
  for (int k = 0; k < 8; ++k) {
    acc[k] += __shfl_xor(acc[k], 16);
    acc[k] += __shfl_xor(acc[k], 32);
  }
  float invz = 1.f / zp;
  float s = 0.f;
#pragma unroll
  for (int k = 0; k < 8; ++k)
    s += (acc[k] * invz + b2[ql * 8 + k]) * fcw[ql * 8 + k];
#pragma unroll
  for (int off = 8; off > 0; off >>= 1) s += __shfl_xor(s, off);
  if (lane == 0) out[n] = s + fcb[0];
}

extern "C" void kernel_launch(void* const* d_in, const int* in_sizes, int n_in,
                              void* d_out, int out_size, void* d_ws, size_t ws_size,
                              hipStream_t stream) {
  const float* x   = (const float*)d_in[0];
  const int*   ei  = (const int*)d_in[1];
  const float* W1  = (const float*)d_in[2];
  const float* a1s = (const float*)d_in[3];
  const float* a1d = (const float*)d_in[4];
  const float* b1  = (const float*)d_in[5];
  const float* W2  = (const float*)d_in[6];
  const float* a2s = (const float*)d_in[7];
  const float* a2d = (const float*)d_in[8];
  const float* b2  = (const float*)d_in[9];
  const float* fcw = (const float*)d_in[10];
  const float* fcb = (const float*)d_in[11];
  float* out = (float*)d_out;
  (void)d_ws; (void)ws_size; (void)in_sizes; (void)n_in; (void)out_size;

  // ---- init (zero_deg | convw | prep1) + CSR build ----
  k_init<<<713, 256, 0, stream>>>(W1, W2, a1s, a1d);
  k_hist<<<(kEt + 255) / 256, 256, 0, stream>>>(ei);
  k_scan<<<1, 1024, 0, stream>>>();
  k_scatter<<<(kEt + 255) / 256, 256, 0, stream>>>(ei);

  // ---- layer 1 ----
  k_scores1x<<<(kN * 64 + 255) / 256, 256, 0, stream>>>(x);
  k_agg1x<<<(kN * 64 + 255) / 256, 256, 0, stream>>>(x);
  dim3 ge(1, (kN + 63) / 64, 4);
  k_exp<<<ge, 256, 0, stream>>>(b1);

  // ---- layer 2 ----
  dim3 g2(1, (kN + 63) / 64, 2);
  k_gemm2<<<g2, 256, 0, stream>>>();
  k_scores2<<<(kN * 64 + 255) / 256, 256, 0, stream>>>(a2s, a2d);
  k_agg2x<<<(kN * 64 + 255) / 256, 256, 0, stream>>>(b2, fcw, fcb, out);
}

// Round 14
// 683.026 us; speedup vs baseline: 1.0033x; 1.0033x over previous
//
#include <hip/hip_runtime.h>
#include <cstdint>
#include <cstddef>

constexpr int kN   = 50000;          // nodes
constexpr int kE   = 800000;         // edges (without self loops)
constexpr int kEt  = kE + kN;        // edges + self loops
constexpr float kSlope = 0.2f;       // leaky relu slope

typedef __attribute__((ext_vector_type(8))) short bf8_t;    // 8 bf16 = 4 VGPRs
typedef __attribute__((ext_vector_type(4))) float f4_t;
typedef __attribute__((ext_vector_type(16))) float f16_t;   // 32x32 acc

// ---------------- static device workspace (d_ws unused) ---------------------
__device__ __align__(16) unsigned g_aggx_p[(size_t)kN * 512];       // agg of x packed hi|lo
__device__ __align__(16) unsigned g_h1p[(size_t)kN * 512];          // h1 packed hi|lo
__device__ __align__(16) unsigned short g_w1t_h[4 * 128 * 128];     // W1^T per head, hi
__device__ __align__(16) unsigned short g_w1t_l[4 * 128 * 128];
__device__ __align__(16) unsigned short g_w2t_h[128 * 512];         // W2^T, hi
__device__ __align__(16) unsigned short g_w2t_l[128 * 512];
__device__ __align__(16) float g_h2  [(size_t)kN * 128];  // layer-2 pre-agg features
__device__ __align__(16) float g_h2p [2][(size_t)kN * 128]; // split-K partials
__device__ __align__(16) float g_es1[kN * 4];
__device__ __align__(16) float g_ed1[kN * 4];
__device__ float g_es2[kN];
__device__ float g_ed2[kN];
__device__ __align__(16) float g_p1s[4 * 128];  // folded W1_h @ a1_src_h
__device__ __align__(16) float g_p1d[4 * 128];
// CSR by destination:
__device__ int g_deg[kN];
__device__ int g_ptr[kN + 1];
__device__ int g_cur[kN];
__device__ int g_srcs[kEt];

__device__ __forceinline__ float lrelu(float x) { return x > 0.f ? x : kSlope * x; }

// round-to-nearest-even f32 -> bf16
__device__ __forceinline__ unsigned short f2bf(float v, float& hi_f) {
  unsigned u = __float_as_uint(v);
  unsigned r = (u + 0x7FFFu + ((u >> 16) & 1u)) & 0xFFFF0000u;
  hi_f = __uint_as_float(r);
  return (unsigned short)(r >> 16);
}
__device__ __forceinline__ void split_bf(float v, unsigned short& h, unsigned short& l) {
  float hf, lf;
  h = f2bf(v, hf);
  l = f2bf(v - hf, lf);
}
__device__ __forceinline__ unsigned pack_bf(float v) {
  unsigned short hb, lb;
  split_bf(v, hb, lb);
  return ((unsigned)hb << 16) | lb;
}

// unpack 8 packed (hi<<16|lo) u32 -> hi bf8 + lo bf8
__device__ __forceinline__ void unpack8(uint4 u0, uint4 u1, bf8_t& h, bf8_t& l) {
  unsigned uu[8] = {u0.x, u0.y, u0.z, u0.w, u1.x, u1.y, u1.z, u1.w};
  unsigned hp[4], lp[4];
#pragma unroll
  for (int i = 0; i < 4; ++i) {
    hp[i] = (uu[2 * i] >> 16) | (uu[2 * i + 1] & 0xFFFF0000u);
    lp[i] = (uu[2 * i] & 0xFFFFu) | (uu[2 * i + 1] << 16);
  }
  uint4 hv = make_uint4(hp[0], hp[1], hp[2], hp[3]);
  uint4 lv = make_uint4(lp[0], lp[1], lp[2], lp[3]);
  h = *(bf8_t*)&hv;
  l = *(bf8_t*)&lv;
}

// ------- merged init: zero_deg (blocks 0..196) | convw (197..708) | prep1 ---
__global__ __launch_bounds__(256) void k_init(const float* __restrict__ W1,
    const float* __restrict__ W2, const float* __restrict__ a1s,
    const float* __restrict__ a1d) {
  const int b = blockIdx.x, t = threadIdx.x;
  if (b < 197) {
    int i = b * 256 + t;
    if (i < kN) g_deg[i] = 0;
  } else if (b < 709) {
    int gid = (b - 197) * 256 + t;   // 0..131071
    if (gid < 65536) {
      int h = gid >> 14, rem = gid & 16383;
      int c = rem >> 7, j = rem & 127;
      float v = W1[(size_t)c * 512 + h * 128 + j];
      unsigned short hh, ll;
      split_bf(v, hh, ll);
      size_t o = ((size_t)h * 128 + j) * 128 + c;
      g_w1t_h[o] = hh; g_w1t_l[o] = ll;
    } else {
      int g2 = gid - 65536;
      int k = g2 >> 7, j = g2 & 127;
      float v = W2[(size_t)k * 128 + j];
      unsigned short hh, ll;
      split_bf(v, hh, ll);
      size_t o = (size_t)j * 512 + k;
      g_w2t_h[o] = hh; g_w2t_l[o] = ll;
    }
  } else {
    int gid = (b - 709) * 256 + t;   // 0..1023
    int which = gid >> 9, idx = gid & 511;
    int h = idx >> 7, k = idx & 127;
    const float* a = which ? a1d : a1s;
    const float* wrow = W1 + (size_t)k * 512 + h * 128;
    float s = 0.f;
#pragma unroll 8
    for (int c = 0; c < 128; ++c) s += wrow[c] * a[h * 128 + c];
    (which ? g_p1d : g_p1s)[idx] = s;
  }
}

__global__ __launch_bounds__(256) void k_hist(const int* __restrict__ ei) {
  int e = blockIdx.x * 256 + threadIdx.x;
  if (e >= kEt) return;
  int d = (e < kE) ? ei[kE + e] : e - kE;
  atomicAdd(&g_deg[d], 1);
}

__global__ __launch_bounds__(1024) void k_scan() {
  __shared__ int s_sum[1024];
  const int t = threadIdx.x;
  const int chunk = (kN + 1023) / 1024;        // 49
  const int lo = t * chunk, hi = min(lo + chunk, kN);
  int sum = 0;
  for (int i = lo; i < hi; ++i) sum += g_deg[i];
  s_sum[t] = sum;
  __syncthreads();
  for (int off = 1; off < 1024; off <<= 1) {
    int xv = s_sum[t];
    int yv = (t >= off) ? s_sum[t - off] : 0;
    __syncthreads();
    s_sum[t] = xv + yv;
    __syncthreads();
  }
  int run = s_sum[t] - sum;
  for (int i = lo; i < hi; ++i) {
    g_ptr[i] = run;
    g_cur[i] = run;
    run += g_deg[i];
  }
  if (t == 1023) g_ptr[kN] = run;
}

__global__ __launch_bounds__(256) void k_scatter(const int* __restrict__ ei) {
  int e = blockIdx.x * 256 + threadIdx.x;
  if (e >= kEt) return;
  int s, d;
  if (e < kE) { s = ei[e]; d = ei[kE + e]; } else { s = d = e - kE; }
  int slot = atomicAdd(&g_cur[d], 1);
  g_srcs[slot] = s;
}

// ---- layer-1 scores directly from x ----
__global__ __launch_bounds__(256) void k_scores1x(const float* __restrict__ x) {
  const int lane = threadIdx.x & 63;
  const int n = (blockIdx.x * 256 + threadIdx.x) >> 6;
  if (n >= kN) return;
  float x0 = x[(size_t)n * 128 + lane];
  float x1 = x[(size_t)n * 128 + 64 + lane];
  float s[4], d[4];
#pragma unroll
  for (int h = 0; h < 4; ++h) {
    s[h] = x0 * g_p1s[h * 128 + lane] + x1 * g_p1s[h * 128 + 64 + lane];
    d[h] = x0 * g_p1d[h * 128 + lane] + x1 * g_p1d[h * 128 + 64 + lane];
  }
#pragma unroll
  for (int off = 32; off > 0; off >>= 1) {
#pragma unroll
    for (int h = 0; h < 4; ++h) {
      s[h] += __shfl_down(s[h], off);
      d[h] += __shfl_down(d[h], off);
    }
  }
  if (lane == 0) {
    *(float4*)(g_es1 + (size_t)n * 4) = make_float4(s[0], s[1], s[2], s[3]);
    *(float4*)(g_ed1 + (size_t)n * 4) = make_float4(d[0], d[1], d[2], d[3]);
  }
}

// ---- layer-1 aggregation: 4 edges/iter (16-lane quarters), 2xfloat4/lane ---
__global__ __launch_bounds__(256) void k_agg1x(const float* __restrict__ x) {
  const int lane = threadIdx.x & 63;
  const int n = (blockIdx.x * 256 + threadIdx.x) >> 6;
  if (n >= kN) return;
  const int beg = g_ptr[n], end = g_ptr[n + 1];
  const float4 ed = *(const float4*)(g_ed1 + (size_t)n * 4);
  const int qt = lane >> 4, ql = lane & 15;
  float z0 = 0.f, z1 = 0.f, z2 = 0.f, z3 = 0.f;
  float acc[4][8] = {};
  for (int base = beg; base < end; base += 64) {
    const int cnt = min(64, end - base);
    int s = 0;
    float w0 = 0.f, w1 = 0.f, w2 = 0.f, w3 = 0.f;
    if (lane < cnt) {
      s = g_srcs[base + lane];
      float4 es = *(const float4*)(g_es1 + (size_t)s * 4);
      w0 = __expf(lrelu(es.x + ed.x));
      w1 = __expf(lrelu(es.y + ed.y));
      w2 = __expf(lrelu(es.z + ed.z));
      w3 = __expf(lrelu(es.w + ed.w));
      z0 += w0; z1 += w1; z2 += w2; z3 += w3;
    }
    const int quads = (cnt + 3) >> 2;
#pragma unroll 2
    for (int p = 0; p < quads; ++p) {
      int ei = 4 * p + qt;
      int   sj = __shfl(s, ei);
      float b0 = __shfl(w0, ei), b1 = __shfl(w1, ei);
      float b2 = __shfl(w2, ei), b3 = __shfl(w3, ei);
      const float* xp = x + (size_t)sj * 128 + ql * 8;
      float4 f0 = *(const float4*)xp;
      float4 f1 = *(const float4*)(xp + 4);
      float fv[8] = {f0.x, f0.y, f0.z, f0.w, f1.x, f1.y, f1.z, f1.w};
#pragma unroll
      for (int k = 0; k < 8; ++k) {
        acc[0][k] += b0 * fv[k];
        acc[1][k] += b1 * fv[k];
        acc[2][k] += b2 * fv[k];
        acc[3][k] += b3 * fv[k];
      }
    }
  }
#pragma unroll
  for (int h = 0; h < 4; ++h)
#pragma unroll
    for (int k = 0; k < 8; ++k) {
      acc[h][k] += __shfl_xor(acc[h][k], 16);
      acc[h][k] += __shfl_xor(acc[h][k], 32);
    }
#pragma unroll
  for (int off = 1; off < 64; off <<= 1) {
    z0 += __shfl_xor(z0, off); z1 += __shfl_xor(z1, off);
    z2 += __shfl_xor(z2, off); z3 += __shfl_xor(z3, off);
  }
  float zh = qt == 0 ? z0 : qt == 1 ? z1 : qt == 2 ? z2 : z3;
  float iz = 1.f / zh;
  unsigned pv[8];
#pragma unroll
  for (int k = 0; k < 8; ++k) {
    float v = (qt == 0 ? acc[0][k] : qt == 1 ? acc[1][k] : qt == 2 ? acc[2][k] : acc[3][k]) * iz;
    pv[k] = pack_bf(v);
  }
  size_t o = (size_t)n * 512 + qt * 128 + ql * 8;
  *(uint4*)(g_aggx_p + o)     = make_uint4(pv[0], pv[1], pv[2], pv[3]);
  *(uint4*)(g_aggx_p + o + 4) = make_uint4(pv[4], pv[5], pv[6], pv[7]);
}

// ------- layer-1 expand: barrier-free, no LDS, 32x32x16 MFMA ----------------
// 64-row x 1-head blocks (grid 782 x 4). Wave w: row-tile w>>1, col-tiles
// (w&1)*2 + {0,1}. D-layout stores are 128 B contiguous (no write amp).
__global__ __launch_bounds__(256) void k_exp(const float* __restrict__ b1) {
  const int t = threadIdx.x;
  const int lane = t & 63, w = t >> 6;
  const int rt = w >> 1, ct0 = (w & 1) * 2;
  const int ln31 = lane & 31, hk = (lane >> 5) * 8;
  const int row0 = blockIdx.y * 64;
  const int h = blockIdx.z;
  f16_t acc0 = {}, acc1 = {};
  const int rA = row0 + rt * 32 + ln31;
  const bool rok = rA < kN;
#pragma unroll
  for (int ks = 0; ks < 128; ks += 16) {
    bf8_t ah, al;
    uint4 u0 = make_uint4(0u, 0u, 0u, 0u), u1 = u0;
    if (rok) {
      const unsigned* p = g_aggx_p + (size_t)rA * 512 + h * 128 + ks + hk;
      u0 = *(const uint4*)p;
      u1 = *(const uint4*)(p + 4);
    }
    unpack8(u0, u1, ah, al);
#pragma unroll
    for (int c = 0; c < 2; ++c) {
      int n = (ct0 + c) * 32 + ln31;
      size_t gb = ((size_t)h * 128 + n) * 128 + ks + hk;
      bf8_t bh = *(const bf8_t*)&g_w1t_h[gb];
      bf8_t bl = *(const bf8_t*)&g_w1t_l[gb];
      f16_t& A = c ? acc1 : acc0;
      A = __builtin_amdgcn_mfma_f32_32x32x16_bf16(ah, bh, A, 0, 0, 0);
      A = __builtin_amdgcn_mfma_f32_32x32x16_bf16(al, bh, A, 0, 0, 0);
      A = __builtin_amdgcn_mfma_f32_32x32x16_bf16(ah, bl, A, 0, 0, 0);
    }
  }
#pragma unroll
  for (int c = 0; c < 2; ++c) {
    int col = (ct0 + c) * 32 + ln31;
    float bv = b1[h * 128 + col];
    const f16_t& A = c ? acc1 : acc0;
#pragma unroll
    for (int reg = 0; reg < 16; ++reg) {
      int rl = (reg & 3) + 8 * (reg >> 2) + ((lane >> 5) << 2);
      int r = row0 + rt * 32 + rl;
      if (r < kN)
        g_h1p[(size_t)r * 512 + h * 128 + col] = pack_bf(fmaxf(A[reg] + bv, 0.f));
    }
  }
}

// ------- layer-2 GEMM: barrier-free, no LDS, split-K=2, 32x32x16 MFMA -------
__global__ __launch_bounds__(256) void k_gemm2() {
  const int t = threadIdx.x;
  const int lane = t & 63, w = t >> 6;
  const int rt = w >> 1, ct0 = (w & 1) * 2;
  const int ln31 = lane & 31, hk = (lane >> 5) * 8;
  const int row0 = blockIdx.y * 64;
  const int z = blockIdx.z;
  f16_t acc0 = {}, acc1 = {};
  const int rA = row0 + rt * 32 + ln31;
  const bool rok = rA < kN;
#pragma unroll 4
  for (int ks = 0; ks < 256; ks += 16) {
    bf8_t ah, al;
    uint4 u0 = make_uint4(0u, 0u, 0u, 0u), u1 = u0;
    if (rok) {
      const unsigned* p = g_h1p + (size_t)rA * 512 + z * 256 + ks + hk;
      u0 = *(const uint4*)p;
      u1 = *(const uint4*)(p + 4);
    }
    unpack8(u0, u1, ah, al);
#pragma unroll
    for (int c = 0; c < 2; ++c) {
      int n = (ct0 + c) * 32 + ln31;
      size_t gb = (size_t)n * 512 + z * 256 + ks + hk;
      bf8_t bh = *(const bf8_t*)&g_w2t_h[gb];
      bf8_t bl = *(const bf8_t*)&g_w2t_l[gb];
      f16_t& A = c ? acc1 : acc0;
      A = __builtin_amdgcn_mfma_f32_32x32x16_bf16(ah, bh, A, 0, 0, 0);
      A = __builtin_amdgcn_mfma_f32_32x32x16_bf16(al, bh, A, 0, 0, 0);
      A = __builtin_amdgcn_mfma_f32_32x32x16_bf16(ah, bl, A, 0, 0, 0);
    }
  }
  float* outp = g_h2p[z];
#pragma unroll
  for (int c = 0; c < 2; ++c) {
    int col = (ct0 + c) * 32 + ln31;
    const f16_t& A = c ? acc1 : acc0;
#pragma unroll
    for (int reg = 0; reg < 16; ++reg) {
      int rl = (reg & 3) + 8 * (reg >> 2) + ((lane >> 5) << 2);
      int r = row0 + rt * 32 + rl;
      if (r < kN) outp[(size_t)r * 128 + col] = A[reg];
    }
  }
}

// ---- fused partial-sum (2 slices) + layer-2 scores; materializes g_h2 ----
__global__ __launch_bounds__(256) void k_scores2(const float* __restrict__ asrc,
                                                 const float* __restrict__ adst) {
  const int lane = threadIdx.x & 63;
  const int n = (blockIdx.x * 256 + threadIdx.x) >> 6;
  if (n >= kN) return;
  const size_t o = (size_t)n * 128;
  float v0 = g_h2p[0][o + lane]      + g_h2p[1][o + lane];
  float v1 = g_h2p[0][o + 64 + lane] + g_h2p[1][o + 64 + lane];
  g_h2[o + lane] = v0;
  g_h2[o + 64 + lane] = v1;
  float s = v0 * asrc[lane] + v1 * asrc[64 + lane];
  float d = v0 * adst[lane] + v1 * adst[64 + lane];
#pragma unroll
  for (int off = 32; off > 0; off >>= 1) {
    s += __shfl_down(s, off);
    d += __shfl_down(d, off);
  }
  if (lane == 0) { g_es2[n] = s; g_ed2[n] = d; }
}

// ---- layer-2 aggregation: 4 edges/iter (quarters) + fused FC ---------------
__global__ __launch_bounds__(256) void k_agg2x(const float* __restrict__ b2,
    const float* __restrict__ fcw, const float* __restrict__ fcb,
    float* __restrict__ out) {
  const int lane = threadIdx.x & 63;
  const int n = (blockIdx.x * 256 + threadIdx.x) >> 6;
  if (n >= kN) return;
  const int beg = g_ptr[n], end = g_ptr[n + 1];
  const float ed = g_ed2[n];
  const int qt = lane >> 4, ql = lane & 15;
  float zp = 0.f;
  float acc[8] = {};
  for (int base = beg; base < end; base += 64) {
    const int cnt = min(64, end - base);
    int s = 0; float w = 0.f;
    if (lane < cnt) {
      s = g_srcs[base + lane];
      w = __expf(lrelu(g_es2[s] + ed));
      zp += w;
    }
    const int quads = (cnt + 3) >> 2;
#pragma unroll 2
    for (int p = 0; p < quads; ++p) {
      int ei = 4 * p + qt;
      int   sj = __shfl(s, ei);
      float wj = __shfl(w, ei);
      const float* hp = g_h2 + (size_t)sj * 128 + ql * 8;
      float4 f0 = *(const float4*)hp;
      float4 f1 = *(const float4*)(hp + 4);
      acc[0] += wj * f0.x; acc[1] += wj * f0.y;
      acc[2] += wj * f0.z; acc[3] += wj * f0.w;
      acc[4] += wj * f1.x; acc[5] += wj * f1.y;
      acc[6] += wj * f1.z; acc[7] += wj * f1.w;
    }
  }
#pragma unroll
  for (int off = 1; off < 64; off <<= 1) zp += __shfl_xor(zp, off);
#pragma unroll
  for (int k = 0; k < 8; ++k) {
    acc[k] += __shfl_xor(acc[k], 16);
    acc[k] += __shfl_xor(acc[k], 32);
  }
  float invz = 1.f / zp;
  float s = 0.f;
#pragma unroll
  for (int k = 0; k < 8; ++k)
    s += (acc[k] * invz + b2[ql * 8 + k]) * fcw[ql * 8 + k];
#pragma unroll
  for (int off = 8; off > 0; off >>= 1) s += __shfl_xor(s, off);
  if (lane == 0) out[n] = s + fcb[0];
}

extern "C" void kernel_launch(void* const* d_in, const int* in_sizes, int n_in,
                              void* d_out, int out_size, void* d_ws, size_t ws_size,
                              hipStream_t stream) {
  const float* x   = (const float*)d_in[0];
  const int*   ei  = (const int*)d_in[1];
  const float* W1  = (const float*)d_in[2];
  const float* a1s = (const float*)d_in[3];
  const float* a1d = (const float*)d_in[4];
  const float* b1  = (const float*)d_in[5];
  const float* W2  = (const float*)d_in[6];
  const float* a2s = (const float*)d_in[7];
  const float* a2d = (const float*)d_in[8];
  const float* b2  = (const float*)d_in[9];
  const float* fcw = (const float*)d_in[10];
  const float* fcb = (const float*)d_in[11];
  float* out = (float*)d_out;
  (void)d_ws; (void)ws_size; (void)in_sizes; (void)n_in; (void)out_size;

  // ---- init (zero_deg | convw | prep1) + CSR build ----
  k_init<<<713, 256, 0, stream>>>(W1, W2, a1s, a1d);
  k_hist<<<(kEt + 255) / 256, 256, 0, stream>>>(ei);
  k_scan<<<1, 1024, 0, stream>>>();
  k_scatter<<<(kEt + 255) / 256, 256, 0, stream>>>(ei);

  // ---- layer 1 ----
  k_scores1x<<<(kN * 64 + 255) / 256, 256, 0, stream>>>(x);
  k_agg1x<<<(kN * 64 + 255) / 256, 256, 0, stream>>>(x);
  dim3 ge(1, (kN + 63) / 64, 4);
  k_exp<<<ge, 256, 0, stream>>>(b1);

  // ---- layer 2 ----
  dim3 g2(1, (kN + 63) / 64, 2);
  k_gemm2<<<g2, 256, 0, stream>>>();
  k_scores2<<<(kN * 64 + 255) / 256, 256, 0, stream>>>(a2s, a2d);
  k_agg2x<<<(kN * 64 + 255) / 256, 256, 0, stream>>>(b2, fcw, fcb, out);
}

// Round 15
// 574.027 us; speedup vs baseline: 1.1938x; 1.1899x over previous
//
#include <hip/hip_runtime.h>
#include <cstdint>
#include <cstddef>

constexpr int kN   = 50000;          // nodes
constexpr int kE   = 800000;         // edges (without self loops)
constexpr int kEt  = kE + kN;        // edges + self loops
constexpr float kSlope = 0.2f;       // leaky relu slope

typedef __attribute__((ext_vector_type(8))) short bf8_t;   // 8 bf16 = 4 VGPRs
typedef __attribute__((ext_vector_type(4))) float f4_t;

// ---------------- static device workspace (d_ws unused) ---------------------
__device__ __align__(16) unsigned short g_aggx_h[(size_t)kN * 512]; // agg of x, bf16 hi
__device__ __align__(16) unsigned short g_aggx_l[(size_t)kN * 512]; // bf16 lo residual
__device__ __align__(16) unsigned short g_w1t_h[4 * 128 * 128];     // W1^T per head, hi
__device__ __align__(16) unsigned short g_w1t_l[4 * 128 * 128];
__device__ __align__(16) unsigned short g_w2t_h[128 * 512];         // W2^T, hi
__device__ __align__(16) unsigned short g_w2t_l[128 * 512];
__device__ __align__(16) float g_h2  [(size_t)kN * 128];  // layer-2 pre-agg features
__device__ __align__(16) float g_es1[kN * 4];
__device__ __align__(16) float g_ed1[kN * 4];
__device__ float g_es2[kN];
__device__ float g_ed2[kN];
__device__ float g_phi[kN];                     // h2[n] . fcw
__device__ float g_c0;                          // b2 . fcw + fcb
__device__ __align__(16) float g_p1s[4 * 128];  // folded W1_h @ a1_src_h
__device__ __align__(16) float g_p1d[4 * 128];
// CSR by destination:
__device__ int g_deg[kN];
__device__ int g_ptr[kN + 1];
__device__ int g_cur[kN];
__device__ int g_srcs[kEt];

__device__ __forceinline__ float lrelu(float x) { return x > 0.f ? x : kSlope * x; }

// round-to-nearest-even f32 -> bf16
__device__ __forceinline__ unsigned short f2bf(float v, float& hi_f) {
  unsigned u = __float_as_uint(v);
  unsigned r = (u + 0x7FFFu + ((u >> 16) & 1u)) & 0xFFFF0000u;
  hi_f = __uint_as_float(r);
  return (unsigned short)(r >> 16);
}
__device__ __forceinline__ void split_bf(float v, unsigned short& h, unsigned short& l) {
  float hf, lf;
  h = f2bf(v, hf);
  l = f2bf(v - hf, lf);
}

// ------- merged init: zero_deg | convw | prep1 | c0 --------------------------
__global__ __launch_bounds__(256) void k_init(const float* __restrict__ W1,
    const float* __restrict__ W2, const float* __restrict__ a1s,
    const float* __restrict__ a1d, const float* __restrict__ b2,
    const float* __restrict__ fcw, const float* __restrict__ fcb) {
  const int b = blockIdx.x, t = threadIdx.x;
  if (b < 197) {
    int i = b * 256 + t;
    if (i < kN) g_deg[i] = 0;
  } else if (b < 709) {
    int gid = (b - 197) * 256 + t;   // 0..131071
    if (gid < 65536) {
      int h = gid >> 14, rem = gid & 16383;
      int c = rem >> 7, j = rem & 127;
      float v = W1[(size_t)c * 512 + h * 128 + j];
      unsigned short hh, ll;
      split_bf(v, hh, ll);
      size_t o = ((size_t)h * 128 + j) * 128 + c;
      g_w1t_h[o] = hh; g_w1t_l[o] = ll;
    } else {
      int g2 = gid - 65536;
      int k = g2 >> 7, j = g2 & 127;
      float v = W2[(size_t)k * 128 + j];
      unsigned short hh, ll;
      split_bf(v, hh, ll);
      size_t o = (size_t)j * 512 + k;
      g_w2t_h[o] = hh; g_w2t_l[o] = ll;
    }
  } else if (b < 713) {
    int gid = (b - 709) * 256 + t;   // 0..1023
    int which = gid >> 9, idx = gid & 511;
    int h = idx >> 7, k = idx & 127;
    const float* a = which ? a1d : a1s;
    const float* wrow = W1 + (size_t)k * 512 + h * 128;
    float s = 0.f;
#pragma unroll 8
    for (int c = 0; c < 128; ++c) s += wrow[c] * a[h * 128 + c];
    (which ? g_p1d : g_p1s)[idx] = s;
  } else {
    // c0 = b2 . fcw + fcb  (first wave only)
    if (t < 64) {
      float s = b2[t] * fcw[t] + b2[64 + t] * fcw[64 + t];
#pragma unroll
      for (int off = 32; off > 0; off >>= 1) s += __shfl_down(s, off);
      if (t == 0) g_c0 = s + fcb[0];
    }
  }
}

__global__ __launch_bounds__(256) void k_hist(const int* __restrict__ ei) {
  int e = blockIdx.x * 256 + threadIdx.x;
  if (e >= kEt) return;
  int d = (e < kE) ? ei[kE + e] : e - kE;
  atomicAdd(&g_deg[d], 1);
}

// single-block (1024 thr) exclusive scan -> g_ptr, g_cur
__global__ __launch_bounds__(1024) void k_scan() {
  __shared__ int s_sum[1024];
  const int t = threadIdx.x;
  const int chunk = (kN + 1023) / 1024;        // 49
  const int lo = t * chunk, hi = min(lo + chunk, kN);
  int sum = 0;
  for (int i = lo; i < hi; ++i) sum += g_deg[i];
  s_sum[t] = sum;
  __syncthreads();
  for (int off = 1; off < 1024; off <<= 1) {
    int xv = s_sum[t];
    int yv = (t >= off) ? s_sum[t - off] : 0;
    __syncthreads();
    s_sum[t] = xv + yv;
    __syncthreads();
  }
  int run = s_sum[t] - sum;
  for (int i = lo; i < hi; ++i) {
    g_ptr[i] = run;
    g_cur[i] = run;
    run += g_deg[i];
  }
  if (t == 1023) g_ptr[kN] = run;
}

__global__ __launch_bounds__(256) void k_scatter(const int* __restrict__ ei) {
  int e = blockIdx.x * 256 + threadIdx.x;
  if (e >= kEt) return;
  int s, d;
  if (e < kE) { s = ei[e]; d = ei[kE + e]; } else { s = d = e - kE; }
  int slot = atomicAdd(&g_cur[d], 1);
  g_srcs[slot] = s;
}

// ---- layer-1 scores directly from x ----
__global__ __launch_bounds__(256) void k_scores1x(const float* __restrict__ x) {
  const int lane = threadIdx.x & 63;
  const int n = (blockIdx.x * 256 + threadIdx.x) >> 6;
  if (n >= kN) return;
  float x0 = x[(size_t)n * 128 + lane];
  float x1 = x[(size_t)n * 128 + 64 + lane];
  float s[4], d[4];
#pragma unroll
  for (int h = 0; h < 4; ++h) {
    s[h] = x0 * g_p1s[h * 128 + lane] + x1 * g_p1s[h * 128 + 64 + lane];
    d[h] = x0 * g_p1d[h * 128 + lane] + x1 * g_p1d[h * 128 + 64 + lane];
  }
#pragma unroll
  for (int off = 32; off > 0; off >>= 1) {
#pragma unroll
    for (int h = 0; h < 4; ++h) {
      s[h] += __shfl_down(s[h], off);
      d[h] += __shfl_down(d[h], off);
    }
  }
  if (lane == 0) {
    *(float4*)(g_es1 + (size_t)n * 4) = make_float4(s[0], s[1], s[2], s[3]);
    *(float4*)(g_ed1 + (size_t)n * 4) = make_float4(d[0], d[1], d[2], d[3]);
  }
}

// ---- layer-1 aggregation: 4 edges/iter (16-lane quarters), 2xfloat4/lane ---
__global__ __launch_bounds__(256) void k_agg1x(const float* __restrict__ x) {
  const int lane = threadIdx.x & 63;
  const int n = (blockIdx.x * 256 + threadIdx.x) >> 6;
  if (n >= kN) return;
  const int beg = g_ptr[n], end = g_ptr[n + 1];
  const float4 ed = *(const float4*)(g_ed1 + (size_t)n * 4);
  const int qt = lane >> 4, ql = lane & 15;
  float z0 = 0.f, z1 = 0.f, z2 = 0.f, z3 = 0.f;
  float acc[4][8] = {};
  for (int base = beg; base < end; base += 64) {
    const int cnt = min(64, end - base);
    int s = 0;
    float w0 = 0.f, w1 = 0.f, w2 = 0.f, w3 = 0.f;
    if (lane < cnt) {
      s = g_srcs[base + lane];
      float4 es = *(const float4*)(g_es1 + (size_t)s * 4);
      w0 = __expf(lrelu(es.x + ed.x));
      w1 = __expf(lrelu(es.y + ed.y));
      w2 = __expf(lrelu(es.z + ed.z));
      w3 = __expf(lrelu(es.w + ed.w));
      z0 += w0; z1 += w1; z2 += w2; z3 += w3;
    }
    const int quads = (cnt + 3) >> 2;
#pragma unroll 2
    for (int p = 0; p < quads; ++p) {
      int ei = 4 * p + qt;
      int   sj = __shfl(s, ei);
      float b0 = __shfl(w0, ei), b1 = __shfl(w1, ei);
      float b2 = __shfl(w2, ei), b3 = __shfl(w3, ei);
      const float* xp = x + (size_t)sj * 128 + ql * 8;
      float4 f0 = *(const float4*)xp;
      float4 f1 = *(const float4*)(xp + 4);
      float fv[8] = {f0.x, f0.y, f0.z, f0.w, f1.x, f1.y, f1.z, f1.w};
#pragma unroll
      for (int k = 0; k < 8; ++k) {
        acc[0][k] += b0 * fv[k];
        acc[1][k] += b1 * fv[k];
        acc[2][k] += b2 * fv[k];
        acc[3][k] += b3 * fv[k];
      }
    }
  }
#pragma unroll
  for (int h = 0; h < 4; ++h)
#pragma unroll
    for (int k = 0; k < 8; ++k) {
      acc[h][k] += __shfl_xor(acc[h][k], 16);
      acc[h][k] += __shfl_xor(acc[h][k], 32);
    }
#pragma unroll
  for (int off = 1; off < 64; off <<= 1) {
    z0 += __shfl_xor(z0, off); z1 += __shfl_xor(z1, off);
    z2 += __shfl_xor(z2, off); z3 += __shfl_xor(z3, off);
  }
  float zh = qt == 0 ? z0 : qt == 1 ? z1 : qt == 2 ? z2 : z3;
  float iz = 1.f / zh;
  float v[8];
#pragma unroll
  for (int k = 0; k < 8; ++k)
    v[k] = (qt == 0 ? acc[0][k] : qt == 1 ? acc[1][k] : qt == 2 ? acc[2][k] : acc[3][k]) * iz;
  ushort4 h0, l0, h1, l1;
  split_bf(v[0], h0.x, l0.x); split_bf(v[1], h0.y, l0.y);
  split_bf(v[2], h0.z, l0.z); split_bf(v[3], h0.w, l0.w);
  split_bf(v[4], h1.x, l1.x); split_bf(v[5], h1.y, l1.y);
  split_bf(v[6], h1.z, l1.z); split_bf(v[7], h1.w, l1.w);
  size_t o = (size_t)n * 512 + qt * 128 + ql * 8;
  *(ushort4*)(g_aggx_h + o) = h0; *(ushort4*)(g_aggx_h + o + 4) = h1;
  *(ushort4*)(g_aggx_l + o) = l0; *(ushort4*)(g_aggx_l + o + 4) = l1;
}

// ------- fused layer-1 expand + layer-2 GEMM, 64-row tiles (r11 best) -------
__global__ __launch_bounds__(256) void k_fused(const float* __restrict__ b1) {
  __shared__ unsigned short smem[9216];     // 18432 B
  unsigned short* S1h = smem;               // A staging [64][40]
  unsigned short* S1l = smem + 2560;
  unsigned short* Hh  = smem;               // h1 chunk [64][72]
  unsigned short* Hl  = smem + 4608;        // (overlaps S1 — barrier-separated)
  const int t = threadIdx.x;
  const int lane = t & 63, w = t >> 6;
  const int wrow = w >> 1, wcol = w & 1;
  const int ln15 = lane & 15, q = lane >> 4, qo = q * 8;
  const int row0 = blockIdx.y * 64;

  f4_t h2acc[2][4] = {};
#pragma unroll 1
  for (int h = 0; h < 4; ++h) {
    f4_t h1acc[2][4] = {};
#pragma unroll 1
    for (int ks = 0; ks < 128; ks += 32) {
      __syncthreads();
      {
        int r = t >> 2, kq = (t & 3) << 3;
        uint4 vh = make_uint4(0u, 0u, 0u, 0u), vl = vh;
        if (row0 + r < kN) {
          size_t ga = (size_t)(row0 + r) * 512 + h * 128 + ks + kq;
          vh = *(const uint4*)&g_aggx_h[ga];
          vl = *(const uint4*)&g_aggx_l[ga];
        }
        *(uint4*)&S1h[r * 40 + kq] = vh;
        *(uint4*)&S1l[r * 40 + kq] = vl;
      }
      __syncthreads();
      bf8_t ah[2], al[2];
#pragma unroll
      for (int i = 0; i < 2; ++i) {
        int ma = (wrow * 32 + i * 16 + ln15) * 40 + qo;
        ah[i] = *(const bf8_t*)&S1h[ma];
        al[i] = *(const bf8_t*)&S1l[ma];
      }
#pragma unroll
      for (int j = 0; j < 4; ++j) {
        size_t gb = ((size_t)h * 128 + wcol * 64 + j * 16 + ln15) * 128 + ks + qo;
        bf8_t bh = *(const bf8_t*)&g_w1t_h[gb];
        bf8_t bl = *(const bf8_t*)&g_w1t_l[gb];
#pragma unroll
        for (int i = 0; i < 2; ++i)
          h1acc[i][j] = __builtin_amdgcn_mfma_f32_16x16x32_bf16(ah[i], bh, h1acc[i][j], 0, 0, 0);
#pragma unroll
        for (int i = 0; i < 2; ++i)
          h1acc[i][j] = __builtin_amdgcn_mfma_f32_16x16x32_bf16(al[i], bh, h1acc[i][j], 0, 0, 0);
#pragma unroll
        for (int i = 0; i < 2; ++i)
          h1acc[i][j] = __builtin_amdgcn_mfma_f32_16x16x32_bf16(ah[i], bl, h1acc[i][j], 0, 0, 0);
      }
    }
    unsigned pk[2][4][4];
#pragma unroll
    for (int j = 0; j < 4; ++j) {
      float bv = b1[h * 128 + wcol * 64 + j * 16 + ln15];
#pragma unroll
      for (int i = 0; i < 2; ++i)
#pragma unroll
        for (int reg = 0; reg < 4; ++reg) {
          float v = fmaxf(h1acc[i][j][reg] + bv, 0.f);
          unsigned short hb, lb;
          split_bf(v, hb, lb);
          pk[i][j][reg] = ((unsigned)hb << 16) | lb;
        }
    }
#pragma unroll 1
    for (int cc = 0; cc < 2; ++cc) {
      __syncthreads();
      if (wcol == cc) {
#pragma unroll
        for (int i = 0; i < 2; ++i)
#pragma unroll
          for (int j = 0; j < 4; ++j)
#pragma unroll
            for (int reg = 0; reg < 4; ++reg) {
              int rl = wrow * 32 + i * 16 + q * 4 + reg;
              int cl = j * 16 + ln15;
              Hh[rl * 72 + cl] = (unsigned short)(pk[i][j][reg] >> 16);
              Hl[rl * 72 + cl] = (unsigned short)(pk[i][j][reg] & 0xFFFFu);
            }
      }
      __syncthreads();
#pragma unroll 1
      for (int kc = 0; kc < 64; kc += 32) {
        bf8_t ah[2], al[2];
#pragma unroll
        for (int i = 0; i < 2; ++i) {
          int ma = (wrow * 32 + i * 16 + ln15) * 72 + kc + qo;
          ah[i] = *(const bf8_t*)&Hh[ma];
          al[i] = *(const bf8_t*)&Hl[ma];
        }
#pragma unroll
        for (int j = 0; j < 4; ++j) {
          size_t gb = (size_t)(wcol * 64 + j * 16 + ln15) * 512 + h * 128 + cc * 64 + kc + qo;
          bf8_t bh = *(const bf8_t*)&g_w2t_h[gb];
          bf8_t bl = *(const bf8_t*)&g_w2t_l[gb];
#pragma unroll
          for (int i = 0; i < 2; ++i)
            h2acc[i][j] = __builtin_amdgcn_mfma_f32_16x16x32_bf16(ah[i], bh, h2acc[i][j], 0, 0, 0);
#pragma unroll
          for (int i = 0; i < 2; ++i)
            h2acc[i][j] = __builtin_amdgcn_mfma_f32_16x16x32_bf16(al[i], bh, h2acc[i][j], 0, 0, 0);
#pragma unroll
          for (int i = 0; i < 2; ++i)
            h2acc[i][j] = __builtin_amdgcn_mfma_f32_16x16x32_bf16(ah[i], bl, h2acc[i][j], 0, 0, 0);
        }
      }
    }
  }
#pragma unroll
  for (int j = 0; j < 4; ++j) {
    int col = wcol * 64 + j * 16 + ln15;
#pragma unroll
    for (int i = 0; i < 2; ++i)
#pragma unroll
      for (int reg = 0; reg < 4; ++reg) {
        int r = row0 + wrow * 32 + i * 16 + q * 4 + reg;
        if (r < kN) g_h2[(size_t)r * 128 + col] = h2acc[i][j][reg];
      }
  }
}

// ---- layer-2 scores + phi (h2 . fcw) ----
__global__ __launch_bounds__(256) void k_scores2(const float* __restrict__ asrc,
    const float* __restrict__ adst, const float* __restrict__ fcw) {
  const int lane = threadIdx.x & 63;
  const int n = (blockIdx.x * 256 + threadIdx.x) >> 6;
  if (n >= kN) return;
  const size_t o = (size_t)n * 128;
  float v0 = g_h2[o + lane];
  float v1 = g_h2[o + 64 + lane];
  float s = v0 * asrc[lane] + v1 * asrc[64 + lane];
  float d = v0 * adst[lane] + v1 * adst[64 + lane];
  float p = v0 * fcw[lane]  + v1 * fcw[64 + lane];
#pragma unroll
  for (int off = 32; off > 0; off >>= 1) {
    s += __shfl_down(s, off);
    d += __shfl_down(d, off);
    p += __shfl_down(p, off);
  }
  if (lane == 0) { g_es2[n] = s; g_ed2[n] = d; g_phi[n] = p; }
}

// ---- layer-2 scalar aggregation + output: out = (sum w*phi)/z + c0 ---------
// FC commutes with the edge aggregation (output is 1-dim) -> gather 4 B/edge.
__global__ __launch_bounds__(256) void k_agg2s(float* __restrict__ out) {
  const int lane = threadIdx.x & 63;
  const int n = (blockIdx.x * 256 + threadIdx.x) >> 6;
  if (n >= kN) return;
  const int beg = g_ptr[n], end = g_ptr[n + 1];
  const float ed = g_ed2[n];
  float zp = 0.f, num = 0.f;
  for (int base = beg; base < end; base += 64) {
    int slot = base + lane;
    if (slot < end) {
      int s = g_srcs[slot];
      float w = __expf(lrelu(g_es2[s] + ed));
      zp += w;
      num += w * g_phi[s];
    }
  }
#pragma unroll
  for (int off = 1; off < 64; off <<= 1) {
    zp  += __shfl_xor(zp, off);
    num += __shfl_xor(num, off);
  }
  if (lane == 0) out[n] = num / zp + g_c0;
}

extern "C" void kernel_launch(void* const* d_in, const int* in_sizes, int n_in,
                              void* d_out, int out_size, void* d_ws, size_t ws_size,
                              hipStream_t stream) {
  const float* x   = (const float*)d_in[0];
  const int*   ei  = (const int*)d_in[1];
  const float* W1  = (const float*)d_in[2];
  const float* a1s = (const float*)d_in[3];
  const float* a1d = (const float*)d_in[4];
  const float* b1  = (const float*)d_in[5];
  const float* W2  = (const float*)d_in[6];
  const float* a2s = (const float*)d_in[7];
  const float* a2d = (const float*)d_in[8];
  const float* b2  = (const float*)d_in[9];
  const float* fcw = (const float*)d_in[10];
  const float* fcb = (const float*)d_in[11];
  float* out = (float*)d_out;
  (void)d_ws; (void)ws_size; (void)in_sizes; (void)n_in; (void)out_size;

  // ---- init (zero_deg | convw | prep1 | c0) + CSR build ----
  k_init<<<714, 256, 0, stream>>>(W1, W2, a1s, a1d, b2, fcw, fcb);
  k_hist<<<(kEt + 255) / 256, 256, 0, stream>>>(ei);
  k_scan<<<1, 1024, 0, stream>>>();
  k_scatter<<<(kEt + 255) / 256, 256, 0, stream>>>(ei);

  // ---- layer 1 ----
  k_scores1x<<<(kN * 64 + 255) / 256, 256, 0, stream>>>(x);
  k_agg1x<<<(kN * 64 + 255) / 256, 256, 0, stream>>>(x);

  // ---- fused expand + layer-2 GEMM (64-row tiles) ----
  dim3 gf(1, (kN + 63) / 64, 1);
  k_fused<<<gf, 256, 0, stream>>>(b1);

  // ---- layer 2 tail: scores+phi, then scalar edge aggregation ----
  k_scores2<<<(kN * 64 + 255) / 256, 256, 0, stream>>>(a2s, a2d, fcw);
  k_agg2s<<<(kN * 64 + 255) / 256, 256, 0, stream>>>(out);
}

// Round 16
// 498.818 us; speedup vs baseline: 1.3738x; 1.1508x over previous
//
#include <hip/hip_runtime.h>
#include <cstdint>
#include <cstddef>

constexpr int kN   = 50000;          // nodes
constexpr int kE   = 800000;         // edges (without self loops)
constexpr int kEt  = kE + kN;        // edges + self loops
constexpr float kSlope = 0.2f;       // leaky relu slope

typedef __attribute__((ext_vector_type(8))) short bf8_t;   // 8 bf16 = 4 VGPRs
typedef __attribute__((ext_vector_type(4))) float f4_t;

// ---------------- static device workspace (d_ws unused) ---------------------
__device__ __align__(16) unsigned short g_aggx_h[(size_t)kN * 512]; // agg of x, bf16 hi
__device__ __align__(16) unsigned short g_aggx_l[(size_t)kN * 512]; // bf16 lo residual
__device__ __align__(16) unsigned short g_w1t_h[4 * 128 * 128];     // W1^T per head, hi
__device__ __align__(16) unsigned short g_w1t_l[4 * 128 * 128];
__device__ __align__(16) float g_u[3][512];     // W2 @ [a2s, a2d, fcw]
__device__ __align__(16) float g_es1[kN * 4];
__device__ __align__(16) float g_ed1[kN * 4];
__device__ float g_es2[kN];
__device__ float g_ed2[kN];
__device__ float g_phi[kN];                     // h2[n] . fcw
__device__ float g_c0;                          // b2 . fcw + fcb
__device__ __align__(16) float g_p1s[4 * 128];  // folded W1_h @ a1_src_h
__device__ __align__(16) float g_p1d[4 * 128];
// CSR by destination:
__device__ int g_deg[kN];
__device__ int g_ptr[kN + 1];
__device__ int g_cur[kN];
__device__ int g_srcs[kEt];

__device__ __forceinline__ float lrelu(float x) { return x > 0.f ? x : kSlope * x; }

__device__ __forceinline__ bf8_t bf8_zero() {
  uint4 z = make_uint4(0u, 0u, 0u, 0u);
  return *(bf8_t*)&z;
}

// round-to-nearest-even f32 -> bf16
__device__ __forceinline__ unsigned short f2bf(float v, float& hi_f) {
  unsigned u = __float_as_uint(v);
  unsigned r = (u + 0x7FFFu + ((u >> 16) & 1u)) & 0xFFFF0000u;
  hi_f = __uint_as_float(r);
  return (unsigned short)(r >> 16);
}
__device__ __forceinline__ void split_bf(float v, unsigned short& h, unsigned short& l) {
  float hf, lf;
  h = f2bf(v, hf);
  l = f2bf(v - hf, lf);
}

// ------- merged init: zero_deg | W1 conv | prep1 | U | c0 -------------------
__global__ __launch_bounds__(256) void k_init(const float* __restrict__ W1,
    const float* __restrict__ W2, const float* __restrict__ a1s,
    const float* __restrict__ a1d, const float* __restrict__ a2s,
    const float* __restrict__ a2d, const float* __restrict__ b2,
    const float* __restrict__ fcw, const float* __restrict__ fcb) {
  const int b = blockIdx.x, t = threadIdx.x;
  if (b < 197) {
    int i = b * 256 + t;
    if (i < kN) g_deg[i] = 0;
  } else if (b < 453) {
    int gid = (b - 197) * 256 + t;   // 0..65535 : W1 -> per-head W1^T hi/lo
    int h = gid >> 14, rem = gid & 16383;
    int c = rem >> 7, j = rem & 127;
    float v = W1[(size_t)c * 512 + h * 128 + j];
    unsigned short hh, ll;
    split_bf(v, hh, ll);
    size_t o = ((size_t)h * 128 + j) * 128 + c;
    g_w1t_h[o] = hh; g_w1t_l[o] = ll;
  } else if (b < 457) {
    int gid = (b - 453) * 256 + t;   // 0..1023 : fold a1 through W1
    int which = gid >> 9, idx = gid & 511;
    int h = idx >> 7, k = idx & 127;
    const float* a = which ? a1d : a1s;
    const float* wrow = W1 + (size_t)k * 512 + h * 128;
    float s = 0.f;
#pragma unroll 8
    for (int c = 0; c < 128; ++c) s += wrow[c] * a[h * 128 + c];
    (which ? g_p1d : g_p1s)[idx] = s;
  } else if (b < 463) {
    int gid = (b - 457) * 256 + t;   // 0..1535 : U[v][k] = W2[k,:] . V_v
    if (gid < 1536) {
      int v = gid >> 9, k = gid & 511;
      const float* vv = v == 0 ? a2s : v == 1 ? a2d : fcw;
      const float* wrow = W2 + (size_t)k * 128;
      float s = 0.f;
#pragma unroll 8
      for (int c = 0; c < 128; ++c) s += wrow[c] * vv[c];
      g_u[v][k] = s;
    }
  } else {
    if (t < 64) {
      float s = b2[t] * fcw[t] + b2[64 + t] * fcw[64 + t];
#pragma unroll
      for (int off = 32; off > 0; off >>= 1) s += __shfl_down(s, off);
      if (t == 0) g_c0 = s + fcb[0];
    }
  }
}

__global__ __launch_bounds__(256) void k_hist(const int* __restrict__ ei) {
  int e = blockIdx.x * 256 + threadIdx.x;
  if (e >= kEt) return;
  int d = (e < kE) ? ei[kE + e] : e - kE;
  atomicAdd(&g_deg[d], 1);
}

// single-block (1024 thr) exclusive scan -> g_ptr, g_cur
__global__ __launch_bounds__(1024) void k_scan() {
  __shared__ int s_sum[1024];
  const int t = threadIdx.x;
  const int chunk = (kN + 1023) / 1024;        // 49
  const int lo = t * chunk, hi = min(lo + chunk, kN);
  int sum = 0;
  for (int i = lo; i < hi; ++i) sum += g_deg[i];
  s_sum[t] = sum;
  __syncthreads();
  for (int off = 1; off < 1024; off <<= 1) {
    int xv = s_sum[t];
    int yv = (t >= off) ? s_sum[t - off] : 0;
    __syncthreads();
    s_sum[t] = xv + yv;
    __syncthreads();
  }
  int run = s_sum[t] - sum;
  for (int i = lo; i < hi; ++i) {
    g_ptr[i] = run;
    g_cur[i] = run;
    run += g_deg[i];
  }
  if (t == 1023) g_ptr[kN] = run;
}

__global__ __launch_bounds__(256) void k_scatter(const int* __restrict__ ei) {
  int e = blockIdx.x * 256 + threadIdx.x;
  if (e >= kEt) return;
  int s, d;
  if (e < kE) { s = ei[e]; d = ei[kE + e]; } else { s = d = e - kE; }
  int slot = atomicAdd(&g_cur[d], 1);
  g_srcs[slot] = s;
}

// ---- layer-1 scores directly from x ----
__global__ __launch_bounds__(256) void k_scores1x(const float* __restrict__ x) {
  const int lane = threadIdx.x & 63;
  const int n = (blockIdx.x * 256 + threadIdx.x) >> 6;
  if (n >= kN) return;
  float x0 = x[(size_t)n * 128 + lane];
  float x1 = x[(size_t)n * 128 + 64 + lane];
  float s[4], d[4];
#pragma unroll
  for (int h = 0; h < 4; ++h) {
    s[h] = x0 * g_p1s[h * 128 + lane] + x1 * g_p1s[h * 128 + 64 + lane];
    d[h] = x0 * g_p1d[h * 128 + lane] + x1 * g_p1d[h * 128 + 64 + lane];
  }
#pragma unroll
  for (int off = 32; off > 0; off >>= 1) {
#pragma unroll
    for (int h = 0; h < 4; ++h) {
      s[h] += __shfl_down(s[h], off);
      d[h] += __shfl_down(d[h], off);
    }
  }
  if (lane == 0) {
    *(float4*)(g_es1 + (size_t)n * 4) = make_float4(s[0], s[1], s[2], s[3]);
    *(float4*)(g_ed1 + (size_t)n * 4) = make_float4(d[0], d[1], d[2], d[3]);
  }
}

// ---- layer-1 aggregation: 4 edges/iter (16-lane quarters), 2xfloat4/lane ---
__global__ __launch_bounds__(256) void k_agg1x(const float* __restrict__ x) {
  const int lane = threadIdx.x & 63;
  const int n = (blockIdx.x * 256 + threadIdx.x) >> 6;
  if (n >= kN) return;
  const int beg = g_ptr[n], end = g_ptr[n + 1];
  const float4 ed = *(const float4*)(g_ed1 + (size_t)n * 4);
  const int qt = lane >> 4, ql = lane & 15;
  float z0 = 0.f, z1 = 0.f, z2 = 0.f, z3 = 0.f;
  float acc[4][8] = {};
  for (int base = beg; base < end; base += 64) {
    const int cnt = min(64, end - base);
    int s = 0;
    float w0 = 0.f, w1 = 0.f, w2 = 0.f, w3 = 0.f;
    if (lane < cnt) {
      s = g_srcs[base + lane];
      float4 es = *(const float4*)(g_es1 + (size_t)s * 4);
      w0 = __expf(lrelu(es.x + ed.x));
      w1 = __expf(lrelu(es.y + ed.y));
      w2 = __expf(lrelu(es.z + ed.z));
      w3 = __expf(lrelu(es.w + ed.w));
      z0 += w0; z1 += w1; z2 += w2; z3 += w3;
    }
    const int quads = (cnt + 3) >> 2;
#pragma unroll 2
    for (int p = 0; p < quads; ++p) {
      int ei = 4 * p + qt;
      int   sj = __shfl(s, ei);
      float b0 = __shfl(w0, ei), b1 = __shfl(w1, ei);
      float b2 = __shfl(w2, ei), b3 = __shfl(w3, ei);
      const float* xp = x + (size_t)sj * 128 + ql * 8;
      float4 f0 = *(const float4*)xp;
      float4 f1 = *(const float4*)(xp + 4);
      float fv[8] = {f0.x, f0.y, f0.z, f0.w, f1.x, f1.y, f1.z, f1.w};
#pragma unroll
      for (int k = 0; k < 8; ++k) {
        acc[0][k] += b0 * fv[k];
        acc[1][k] += b1 * fv[k];
        acc[2][k] += b2 * fv[k];
        acc[3][k] += b3 * fv[k];
      }
    }
  }
#pragma unroll
  for (int h = 0; h < 4; ++h)
#pragma unroll
    for (int k = 0; k < 8; ++k) {
      acc[h][k] += __shfl_xor(acc[h][k], 16);
      acc[h][k] += __shfl_xor(acc[h][k], 32);
    }
#pragma unroll
  for (int off = 1; off < 64; off <<= 1) {
    z0 += __shfl_xor(z0, off); z1 += __shfl_xor(z1, off);
    z2 += __shfl_xor(z2, off); z3 += __shfl_xor(z3, off);
  }
  float zh = qt == 0 ? z0 : qt == 1 ? z1 : qt == 2 ? z2 : z3;
  float iz = 1.f / zh;
  float v[8];
#pragma unroll
  for (int k = 0; k < 8; ++k)
    v[k] = (qt == 0 ? acc[0][k] : qt == 1 ? acc[1][k] : qt == 2 ? acc[2][k] : acc[3][k]) * iz;
  ushort4 h0, l0, h1, l1;
  split_bf(v[0], h0.x, l0.x); split_bf(v[1], h0.y, l0.y);
  split_bf(v[2], h0.z, l0.z); split_bf(v[3], h0.w, l0.w);
  split_bf(v[4], h1.x, l1.x); split_bf(v[5], h1.y, l1.y);
  split_bf(v[6], h1.z, l1.z); split_bf(v[7], h1.w, l1.w);
  size_t o = (size_t)n * 512 + qt * 128 + ql * 8;
  *(ushort4*)(g_aggx_h + o) = h0; *(ushort4*)(g_aggx_h + o + 4) = h1;
  *(ushort4*)(g_aggx_l + o) = l0; *(ushort4*)(g_aggx_l + o + 4) = l1;
}

// ------- fused layer-1 expand + layer-2 projections -------------------------
// Per 64-row tile: per head, MFMA h1 = aggx_h @ W1_h (direct global fragment
// loads, barrier-free), relu+bias in registers, then dot with U columns to
// accumulate es2/ed2/phi per row. Layer-2 GEMM and h2 are never materialized.
__global__ __launch_bounds__(256) void k_fused(const float* __restrict__ b1) {
  __shared__ float sred[2][64][3];
  const int t = threadIdx.x;
  const int lane = t & 63, w = t >> 6;
  const int wrow = w >> 1, wcol = w & 1;
  const int ln15 = lane & 15, q = lane >> 4, qo = q * 8;
  const int row0 = blockIdx.y * 64;

  float part[2][4][3] = {};      // [i][reg][v]
#pragma unroll 1
  for (int h = 0; h < 4; ++h) {
    f4_t h1acc[2][4] = {};
#pragma unroll
    for (int ks = 0; ks < 128; ks += 32) {
      bf8_t ah[2], al[2];
#pragma unroll
      for (int i = 0; i < 2; ++i) {
        int r = row0 + wrow * 32 + i * 16 + ln15;
        ah[i] = bf8_zero(); al[i] = bf8_zero();
        if (r < kN) {
          size_t ga = (size_t)r * 512 + h * 128 + ks + qo;
          ah[i] = *(const bf8_t*)&g_aggx_h[ga];
          al[i] = *(const bf8_t*)&g_aggx_l[ga];
        }
      }
#pragma unroll
      for (int j = 0; j < 4; ++j) {
        size_t gb = ((size_t)h * 128 + wcol * 64 + j * 16 + ln15) * 128 + ks + qo;
        bf8_t bh = *(const bf8_t*)&g_w1t_h[gb];
        bf8_t bl = *(const bf8_t*)&g_w1t_l[gb];
#pragma unroll
        for (int i = 0; i < 2; ++i)
          h1acc[i][j] = __builtin_amdgcn_mfma_f32_16x16x32_bf16(ah[i], bh, h1acc[i][j], 0, 0, 0);
#pragma unroll
        for (int i = 0; i < 2; ++i)
          h1acc[i][j] = __builtin_amdgcn_mfma_f32_16x16x32_bf16(al[i], bh, h1acc[i][j], 0, 0, 0);
#pragma unroll
        for (int i = 0; i < 2; ++i)
          h1acc[i][j] = __builtin_amdgcn_mfma_f32_16x16x32_bf16(ah[i], bl, h1acc[i][j], 0, 0, 0);
      }
    }
    // epilogue: relu(h1+b1) dotted with U columns, accumulated per row
#pragma unroll
    for (int j = 0; j < 4; ++j) {
      int col = h * 128 + wcol * 64 + j * 16 + ln15;
      float bv = b1[col];
      float u0 = g_u[0][col], u1 = g_u[1][col], u2 = g_u[2][col];
#pragma unroll
      for (int i = 0; i < 2; ++i)
#pragma unroll
        for (int reg = 0; reg < 4; ++reg) {
          float v = fmaxf(h1acc[i][j][reg] + bv, 0.f);
          part[i][reg][0] += v * u0;
          part[i][reg][1] += v * u1;
          part[i][reg][2] += v * u2;
        }
    }
  }
  // reduce over the 16 lanes of each quad-group (same q)
#pragma unroll
  for (int off = 1; off < 16; off <<= 1)
#pragma unroll
    for (int i = 0; i < 2; ++i)
#pragma unroll
      for (int reg = 0; reg < 4; ++reg)
#pragma unroll
        for (int v = 0; v < 3; ++v)
          part[i][reg][v] += __shfl_xor(part[i][reg][v], off);
  if (ln15 == 0) {
#pragma unroll
    for (int i = 0; i < 2; ++i)
#pragma unroll
      for (int reg = 0; reg < 4; ++reg) {
        int rl = wrow * 32 + i * 16 + q * 4 + reg;
#pragma unroll
        for (int v = 0; v < 3; ++v) sred[wcol][rl][v] = part[i][reg][v];
      }
  }
  __syncthreads();
  if (t < 192) {
    int row = t / 3, v = t - row * 3;
    float s = sred[0][row][v] + sred[1][row][v];
    int r = row0 + row;
    if (r < kN) (v == 0 ? g_es2 : v == 1 ? g_ed2 : g_phi)[r] = s;
  }
}

// ---- layer-2 scalar aggregation + output: out = (sum w*phi)/z + c0 ---------
__global__ __launch_bounds__(256) void k_agg2s(float* __restrict__ out) {
  const int lane = threadIdx.x & 63;
  const int n = (blockIdx.x * 256 + threadIdx.x) >> 6;
  if (n >= kN) return;
  const int beg = g_ptr[n], end = g_ptr[n + 1];
  const float ed = g_ed2[n];
  float zp = 0.f, num = 0.f;
  for (int base = beg; base < end; base += 64) {
    int slot = base + lane;
    if (slot < end) {
      int s = g_srcs[slot];
      float w = __expf(lrelu(g_es2[s] + ed));
      zp += w;
      num += w * g_phi[s];
    }
  }
#pragma unroll
  for (int off = 1; off < 64; off <<= 1) {
    zp  += __shfl_xor(zp, off);
    num += __shfl_xor(num, off);
  }
  if (lane == 0) out[n] = num / zp + g_c0;
}

extern "C" void kernel_launch(void* const* d_in, const int* in_sizes, int n_in,
                              void* d_out, int out_size, void* d_ws, size_t ws_size,
                              hipStream_t stream) {
  const float* x   = (const float*)d_in[0];
  const int*   ei  = (const int*)d_in[1];
  const float* W1  = (const float*)d_in[2];
  const float* a1s = (const float*)d_in[3];
  const float* a1d = (const float*)d_in[4];
  const float* b1  = (const float*)d_in[5];
  const float* W2  = (const float*)d_in[6];
  const float* a2s = (const float*)d_in[7];
  const float* a2d = (const float*)d_in[8];
  const float* b2  = (const float*)d_in[9];
  const float* fcw = (const float*)d_in[10];
  const float* fcb = (const float*)d_in[11];
  float* out = (float*)d_out;
  (void)d_ws; (void)ws_size; (void)in_sizes; (void)n_in; (void)out_size;

  // ---- init (zero_deg | W1 conv | prep1 | U | c0) + CSR build ----
  k_init<<<464, 256, 0, stream>>>(W1, W2, a1s, a1d, a2s, a2d, b2, fcw, fcb);
  k_hist<<<(kEt + 255) / 256, 256, 0, stream>>>(ei);
  k_scan<<<1, 1024, 0, stream>>>();
  k_scatter<<<(kEt + 255) / 256, 256, 0, stream>>>(ei);

  // ---- layer 1 ----
  k_scores1x<<<(kN * 64 + 255) / 256, 256, 0, stream>>>(x);
  k_agg1x<<<(kN * 64 + 255) / 256, 256, 0, stream>>>(x);

  // ---- fused expand + layer-2 projections (no layer-2 GEMM) ----
  dim3 gf(1, (kN + 63) / 64, 1);
  k_fused<<<gf, 256, 0, stream>>>(b1);

  // ---- layer-2 scalar edge aggregation + output ----
  k_agg2s<<<(kN * 64 + 255) / 256, 256, 0, stream>>>(out);
}

// Round 17
// 402.575 us; speedup vs baseline: 1.7022x; 1.2391x over previous
//
#include <hip/hip_runtime.h>
#include <cstdint>
#include <cstddef>

constexpr int kN   = 50000;          // nodes
constexpr int kE   = 800000;         // edges (without self loops)
constexpr int kEt  = kE + kN;        // edges + self loops
constexpr float kSlope = 0.2f;       // leaky relu slope
constexpr int kScanB = (kN + 255) / 256;   // 196 scan blocks

typedef __attribute__((ext_vector_type(8))) short bf8_t;   // 8 bf16 = 4 VGPRs
typedef __attribute__((ext_vector_type(4))) float f4_t;

// ---------------- static device workspace (d_ws unused) ---------------------
__device__ __align__(16) unsigned short g_aggx_h[(size_t)kN * 512]; // agg of x, bf16 hi
__device__ __align__(16) unsigned short g_aggx_l[(size_t)kN * 512]; // bf16 lo residual
__device__ __align__(16) unsigned short g_w1t_h[4 * 128 * 128];     // W1^T per head, hi
__device__ __align__(16) unsigned short g_w1t_l[4 * 128 * 128];
__device__ __align__(16) float g_u[3][512];     // W2 @ [a2s, a2d, fcw]
__device__ __align__(16) float g_es1[kN * 4];
__device__ __align__(16) float g_ed1[kN * 4];
__device__ float g_es2[kN];
__device__ float g_ed2[kN];
__device__ float g_phi[kN];                     // h2[n] . fcw
__device__ float g_c0;                          // b2 . fcw + fcb
__device__ __align__(16) float g_p1s[4 * 128];  // folded W1_h @ a1_src_h
__device__ __align__(16) float g_p1d[4 * 128];
// CSR by destination:
__device__ int g_deg[kN];
__device__ int g_ptr[kN + 1];
__device__ int g_cur[kN];
__device__ int g_srcs[kEt];
__device__ int g_bsum[kScanB];
__device__ int g_boff[kScanB];

__device__ __forceinline__ float lrelu(float x) { return x > 0.f ? x : kSlope * x; }

__device__ __forceinline__ bf8_t bf8_zero() {
  uint4 z = make_uint4(0u, 0u, 0u, 0u);
  return *(bf8_t*)&z;
}

// round-to-nearest-even f32 -> bf16
__device__ __forceinline__ unsigned short f2bf(float v, float& hi_f) {
  unsigned u = __float_as_uint(v);
  unsigned r = (u + 0x7FFFu + ((u >> 16) & 1u)) & 0xFFFF0000u;
  hi_f = __uint_as_float(r);
  return (unsigned short)(r >> 16);
}
__device__ __forceinline__ void split_bf(float v, unsigned short& h, unsigned short& l) {
  float hf, lf;
  h = f2bf(v, hf);
  l = f2bf(v - hf, lf);
}

// ------- merged init: zero_deg | W1 conv | prep1 | U | c0 -------------------
__global__ __launch_bounds__(256) void k_init(const float* __restrict__ W1,
    const float* __restrict__ W2, const float* __restrict__ a1s,
    const float* __restrict__ a1d, const float* __restrict__ a2s,
    const float* __restrict__ a2d, const float* __restrict__ b2,
    const float* __restrict__ fcw, const float* __restrict__ fcb) {
  const int b = blockIdx.x, t = threadIdx.x;
  if (b < 197) {
    int i = b * 256 + t;
    if (i < kN) g_deg[i] = 0;
  } else if (b < 453) {
    int gid = (b - 197) * 256 + t;   // 0..65535 : W1 -> per-head W1^T hi/lo
    int h = gid >> 14, rem = gid & 16383;
    int c = rem >> 7, j = rem & 127;
    float v = W1[(size_t)c * 512 + h * 128 + j];
    unsigned short hh, ll;
    split_bf(v, hh, ll);
    size_t o = ((size_t)h * 128 + j) * 128 + c;
    g_w1t_h[o] = hh; g_w1t_l[o] = ll;
  } else if (b < 457) {
    int gid = (b - 453) * 256 + t;   // 0..1023 : fold a1 through W1
    int which = gid >> 9, idx = gid & 511;
    int h = idx >> 7, k = idx & 127;
    const float* a = which ? a1d : a1s;
    const float* wrow = W1 + (size_t)k * 512 + h * 128;
    float s = 0.f;
#pragma unroll 8
    for (int c = 0; c < 128; ++c) s += wrow[c] * a[h * 128 + c];
    (which ? g_p1d : g_p1s)[idx] = s;
  } else if (b < 463) {
    int gid = (b - 457) * 256 + t;   // 0..1535 : U[v][k] = W2[k,:] . V_v
    if (gid < 1536) {
      int v = gid >> 9, k = gid & 511;
      const float* vv = v == 0 ? a2s : v == 1 ? a2d : fcw;
      const float* wrow = W2 + (size_t)k * 128;
      float s = 0.f;
#pragma unroll 8
      for (int c = 0; c < 128; ++c) s += wrow[c] * vv[c];
      g_u[v][k] = s;
    }
  } else {
    if (t < 64) {
      float s = b2[t] * fcw[t] + b2[64 + t] * fcw[64 + t];
#pragma unroll
      for (int off = 32; off > 0; off >>= 1) s += __shfl_down(s, off);
      if (t == 0) g_c0 = s + fcb[0];
    }
  }
}

__global__ __launch_bounds__(256) void k_hist(const int* __restrict__ ei) {
  int e = blockIdx.x * 256 + threadIdx.x;
  if (e >= kEt) return;
  int d = (e < kE) ? ei[kE + e] : e - kE;
  atomicAdd(&g_deg[d], 1);
}

// ---- parallel scan, phase A: per-256-chunk LDS scan + block sums -----------
__global__ __launch_bounds__(256) void k_scanA() {
  __shared__ int s[256];
  const int b = blockIdx.x, t = threadIdx.x;
  const int i = b * 256 + t;
  int d = (i < kN) ? g_deg[i] : 0;
  s[t] = d;
  __syncthreads();
  for (int off = 1; off < 256; off <<= 1) {
    int v = s[t];
    int u = (t >= off) ? s[t - off] : 0;
    __syncthreads();
    s[t] = v + u;
    __syncthreads();
  }
  if (t == 255) g_bsum[b] = s[255];
  if (i < kN) g_ptr[i] = s[t] - d;   // local exclusive
}

// ---- phase B: single-block scan of 196 block sums -> exclusive offsets -----
__global__ __launch_bounds__(256) void k_scanB() {
  __shared__ int s[256];
  const int t = threadIdx.x;
  int v = (t < kScanB) ? g_bsum[t] : 0;
  s[t] = v;
  __syncthreads();
  for (int off = 1; off < 256; off <<= 1) {
    int a = s[t];
    int u = (t >= off) ? s[t - off] : 0;
    __syncthreads();
    s[t] = a + u;
    __syncthreads();
  }
  if (t < kScanB) g_boff[t] = s[t] - v;
  if (t == 0) g_ptr[kN] = kEt;
}

// ---- phase C: add block offsets, mirror into g_cur -------------------------
__global__ __launch_bounds__(256) void k_scanC() {
  const int b = blockIdx.x, t = threadIdx.x;
  const int i = b * 256 + t;
  if (i >= kN) return;
  int p = g_ptr[i] + g_boff[b];
  g_ptr[i] = p;
  g_cur[i] = p;
}

__global__ __launch_bounds__(256) void k_scatter(const int* __restrict__ ei) {
  int e = blockIdx.x * 256 + threadIdx.x;
  if (e >= kEt) return;
  int s, d;
  if (e < kE) { s = ei[e]; d = ei[kE + e]; } else { s = d = e - kE; }
  int slot = atomicAdd(&g_cur[d], 1);
  g_srcs[slot] = s;
}

// ---- layer-1 scores directly from x ----
__global__ __launch_bounds__(256) void k_scores1x(const float* __restrict__ x) {
  const int lane = threadIdx.x & 63;
  const int n = (blockIdx.x * 256 + threadIdx.x) >> 6;
  if (n >= kN) return;
  float x0 = x[(size_t)n * 128 + lane];
  float x1 = x[(size_t)n * 128 + 64 + lane];
  float s[4], d[4];
#pragma unroll
  for (int h = 0; h < 4; ++h) {
    s[h] = x0 * g_p1s[h * 128 + lane] + x1 * g_p1s[h * 128 + 64 + lane];
    d[h] = x0 * g_p1d[h * 128 + lane] + x1 * g_p1d[h * 128 + 64 + lane];
  }
#pragma unroll
  for (int off = 32; off > 0; off >>= 1) {
#pragma unroll
    for (int h = 0; h < 4; ++h) {
      s[h] += __shfl_down(s[h], off);
      d[h] += __shfl_down(d[h], off);
    }
  }
  if (lane == 0) {
    *(float4*)(g_es1 + (size_t)n * 4) = make_float4(s[0], s[1], s[2], s[3]);
    *(float4*)(g_ed1 + (size_t)n * 4) = make_float4(d[0], d[1], d[2], d[3]);
  }
}

// ---- layer-1 aggregation: 4 edges/iter (16-lane quarters), 2xfloat4/lane ---
__global__ __launch_bounds__(256) void k_agg1x(const float* __restrict__ x) {
  const int lane = threadIdx.x & 63;
  const int n = (blockIdx.x * 256 + threadIdx.x) >> 6;
  if (n >= kN) return;
  const int beg = g_ptr[n], end = g_ptr[n + 1];
  const float4 ed = *(const float4*)(g_ed1 + (size_t)n * 4);
  const int qt = lane >> 4, ql = lane & 15;
  float z0 = 0.f, z1 = 0.f, z2 = 0.f, z3 = 0.f;
  float acc[4][8] = {};
  for (int base = beg; base < end; base += 64) {
    const int cnt = min(64, end - base);
    int s = 0;
    float w0 = 0.f, w1 = 0.f, w2 = 0.f, w3 = 0.f;
    if (lane < cnt) {
      s = g_srcs[base + lane];
      float4 es = *(const float4*)(g_es1 + (size_t)s * 4);
      w0 = __expf(lrelu(es.x + ed.x));
      w1 = __expf(lrelu(es.y + ed.y));
      w2 = __expf(lrelu(es.z + ed.z));
      w3 = __expf(lrelu(es.w + ed.w));
      z0 += w0; z1 += w1; z2 += w2; z3 += w3;
    }
    const int quads = (cnt + 3) >> 2;
#pragma unroll 2
    for (int p = 0; p < quads; ++p) {
      int ei = 4 * p + qt;
      int   sj = __shfl(s, ei);
      float b0 = __shfl(w0, ei), b1 = __shfl(w1, ei);
      float b2 = __shfl(w2, ei), b3 = __shfl(w3, ei);
      const float* xp = x + (size_t)sj * 128 + ql * 8;
      float4 f0 = *(const float4*)xp;
      float4 f1 = *(const float4*)(xp + 4);
      float fv[8] = {f0.x, f0.y, f0.z, f0.w, f1.x, f1.y, f1.z, f1.w};
#pragma unroll
      for (int k = 0; k < 8; ++k) {
        acc[0][k] += b0 * fv[k];
        acc[1][k] += b1 * fv[k];
        acc[2][k] += b2 * fv[k];
        acc[3][k] += b3 * fv[k];
      }
    }
  }
#pragma unroll
  for (int h = 0; h < 4; ++h)
#pragma unroll
    for (int k = 0; k < 8; ++k) {
      acc[h][k] += __shfl_xor(acc[h][k], 16);
      acc[h][k] += __shfl_xor(acc[h][k], 32);
    }
#pragma unroll
  for (int off = 1; off < 64; off <<= 1) {
    z0 += __shfl_xor(z0, off); z1 += __shfl_xor(z1, off);
    z2 += __shfl_xor(z2, off); z3 += __shfl_xor(z3, off);
  }
  float zh = qt == 0 ? z0 : qt == 1 ? z1 : qt == 2 ? z2 : z3;
  float iz = 1.f / zh;
  float v[8];
#pragma unroll
  for (int k = 0; k < 8; ++k)
    v[k] = (qt == 0 ? acc[0][k] : qt == 1 ? acc[1][k] : qt == 2 ? acc[2][k] : acc[3][k]) * iz;
  ushort4 h0, l0, h1, l1;
  split_bf(v[0], h0.x, l0.x); split_bf(v[1], h0.y, l0.y);
  split_bf(v[2], h0.z, l0.z); split_bf(v[3], h0.w, l0.w);
  split_bf(v[4], h1.x, l1.x); split_bf(v[5], h1.y, l1.y);
  split_bf(v[6], h1.z, l1.z); split_bf(v[7], h1.w, l1.w);
  size_t o = (size_t)n * 512 + qt * 128 + ql * 8;
  *(ushort4*)(g_aggx_h + o) = h0; *(ushort4*)(g_aggx_h + o + 4) = h1;
  *(ushort4*)(g_aggx_l + o) = l0; *(ushort4*)(g_aggx_l + o + 4) = l1;
}

// ------- fused layer-1 expand + layer-2 projections -------------------------
__global__ __launch_bounds__(256) void k_fused(const float* __restrict__ b1) {
  __shared__ float sred[2][64][3];
  const int t = threadIdx.x;
  const int lane = t & 63, w = t >> 6;
  const int wrow = w >> 1, wcol = w & 1;
  const int ln15 = lane & 15, q = lane >> 4, qo = q * 8;
  const int row0 = blockIdx.y * 64;

  float part[2][4][3] = {};      // [i][reg][v]
#pragma unroll 1
  for (int h = 0; h < 4; ++h) {
    f4_t h1acc[2][4] = {};
#pragma unroll
    for (int ks = 0; ks < 128; ks += 32) {
      bf8_t ah[2], al[2];
#pragma unroll
      for (int i = 0; i < 2; ++i) {
        int r = row0 + wrow * 32 + i * 16 + ln15;
        ah[i] = bf8_zero(); al[i] = bf8_zero();
        if (r < kN) {
          size_t ga = (size_t)r * 512 + h * 128 + ks + qo;
          ah[i] = *(const bf8_t*)&g_aggx_h[ga];
          al[i] = *(const bf8_t*)&g_aggx_l[ga];
        }
      }
#pragma unroll
      for (int j = 0; j < 4; ++j) {
        size_t gb = ((size_t)h * 128 + wcol * 64 + j * 16 + ln15) * 128 + ks + qo;
        bf8_t bh = *(const bf8_t*)&g_w1t_h[gb];
        bf8_t bl = *(const bf8_t*)&g_w1t_l[gb];
#pragma unroll
        for (int i = 0; i < 2; ++i)
          h1acc[i][j] = __builtin_amdgcn_mfma_f32_16x16x32_bf16(ah[i], bh, h1acc[i][j], 0, 0, 0);
#pragma unroll
        for (int i = 0; i < 2; ++i)
          h1acc[i][j] = __builtin_amdgcn_mfma_f32_16x16x32_bf16(al[i], bh, h1acc[i][j], 0, 0, 0);
#pragma unroll
        for (int i = 0; i < 2; ++i)
          h1acc[i][j] = __builtin_amdgcn_mfma_f32_16x16x32_bf16(ah[i], bl, h1acc[i][j], 0, 0, 0);
      }
    }
    // epilogue: relu(h1+b1) dotted with U columns, accumulated per row
#pragma unroll
    for (int j = 0; j < 4; ++j) {
      int col = h * 128 + wcol * 64 + j * 16 + ln15;
      float bv = b1[col];
      float u0 = g_u[0][col], u1 = g_u[1][col], u2 = g_u[2][col];
#pragma unroll
      for (int i = 0; i < 2; ++i)
#pragma unroll
        for (int reg = 0; reg < 4; ++reg) {
          float v = fmaxf(h1acc[i][j][reg] + bv, 0.f);
          part[i][reg][0] += v * u0;
          part[i][reg][1] += v * u1;
          part[i][reg][2] += v * u2;
        }
    }
  }
  // reduce over the 16 lanes of each quad-group (same q)
#pragma unroll
  for (int off = 1; off < 16; off <<= 1)
#pragma unroll
    for (int i = 0; i < 2; ++i)
#pragma unroll
      for (int reg = 0; reg < 4; ++reg)
#pragma unroll
        for (int v = 0; v < 3; ++v)
          part[i][reg][v] += __shfl_xor(part[i][reg][v], off);
  if (ln15 == 0) {
#pragma unroll
    for (int i = 0; i < 2; ++i)
#pragma unroll
      for (int reg = 0; reg < 4; ++reg) {
        int rl = wrow * 32 + i * 16 + q * 4 + reg;
#pragma unroll
        for (int v = 0; v < 3; ++v) sred[wcol][rl][v] = part[i][reg][v];
      }
  }
  __syncthreads();
  if (t < 192) {
    int row = t / 3, v = t - row * 3;
    float s = sred[0][row][v] + sred[1][row][v];
    int r = row0 + row;
    if (r < kN) (v == 0 ? g_es2 : v == 1 ? g_ed2 : g_phi)[r] = s;
  }
}

// ---- layer-2 scalar aggregation + output: out = (sum w*phi)/z + c0 ---------
__global__ __launch_bounds__(256) void k_agg2s(float* __restrict__ out) {
  const int lane = threadIdx.x & 63;
  const int n = (blockIdx.x * 256 + threadIdx.x) >> 6;
  if (n >= kN) return;
  const int beg = g_ptr[n], end = g_ptr[n + 1];
  const float ed = g_ed2[n];
  float zp = 0.f, num = 0.f;
  for (int base = beg; base < end; base += 64) {
    int slot = base + lane;
    if (slot < end) {
      int s = g_srcs[slot];
      float w = __expf(lrelu(g_es2[s] + ed));
      zp += w;
      num += w * g_phi[s];
    }
  }
#pragma unroll
  for (int off = 1; off < 64; off <<= 1) {
    zp  += __shfl_xor(zp, off);
    num += __shfl_xor(num, off);
  }
  if (lane == 0) out[n] = num / zp + g_c0;
}

extern "C" void kernel_launch(void* const* d_in, const int* in_sizes, int n_in,
                              void* d_out, int out_size, void* d_ws, size_t ws_size,
                              hipStream_t stream) {
  const float* x   = (const float*)d_in[0];
  const int*   ei  = (const int*)d_in[1];
  const float* W1  = (const float*)d_in[2];
  const float* a1s = (const float*)d_in[3];
  const float* a1d = (const float*)d_in[4];
  const float* b1  = (const float*)d_in[5];
  const float* W2  = (const float*)d_in[6];
  const float* a2s = (const float*)d_in[7];
  const float* a2d = (const float*)d_in[8];
  const float* b2  = (const float*)d_in[9];
  const float* fcw = (const float*)d_in[10];
  const float* fcb = (const float*)d_in[11];
  float* out = (float*)d_out;
  (void)d_ws; (void)ws_size; (void)in_sizes; (void)n_in; (void)out_size;

  // ---- init (zero_deg | W1 conv | prep1 | U | c0) + CSR build ----
  k_init<<<464, 256, 0, stream>>>(W1, W2, a1s, a1d, a2s, a2d, b2, fcw, fcb);
  k_hist<<<(kEt + 255) / 256, 256, 0, stream>>>(ei);
  k_scanA<<<kScanB, 256, 0, stream>>>();
  k_scanB<<<1, 256, 0, stream>>>();
  k_scanC<<<kScanB, 256, 0, stream>>>();
  k_scatter<<<(kEt + 255) / 256, 256, 0, stream>>>(ei);

  // ---- layer 1 ----
  k_scores1x<<<(kN * 64 + 255) / 256, 256, 0, stream>>>(x);
  k_agg1x<<<(kN * 64 + 255) / 256, 256, 0, stream>>>(x);

  // ---- fused expand + layer-2 projections (no layer-2 GEMM) ----
  dim3 gf(1, (kN + 63) / 64, 1);
  k_fused<<<gf, 256, 0, stream>>>(b1);

  // ---- layer-2 scalar edge aggregation + output ----
  k_agg2s<<<(kN * 64 + 255) / 256, 256, 0, stream>>>(out);
}

// Round 18
// 370.850 us; speedup vs baseline: 1.8478x; 1.0855x over previous
//
#include <hip/hip_runtime.h>
#include <cstdint>
#include <cstddef>

constexpr int kN   = 50000;          // nodes
constexpr int kE   = 800000;         // edges (without self loops)
constexpr int kEt  = kE + kN;        // edges + self loops
constexpr float kSlope = 0.2f;       // leaky relu slope
constexpr int kScanB = (kN + 255) / 256;   // 196 scan blocks

typedef __attribute__((ext_vector_type(8))) short bf8_t;   // 8 bf16 = 4 VGPRs
typedef __attribute__((ext_vector_type(4))) float f4_t;

// ---------------- static device workspace (d_ws unused) ---------------------
__device__ __align__(16) unsigned short g_aggx[(size_t)kN * 512];   // agg of x, bf16
__device__ __align__(16) unsigned short g_w1t_h[4 * 128 * 128];     // W1^T per head, hi
__device__ __align__(16) unsigned short g_w1t_l[4 * 128 * 128];
__device__ __align__(16) float g_u[3][512];     // W2 @ [a2s, a2d, fcw]
__device__ __align__(16) float g_es1[kN * 4];
__device__ __align__(16) float g_ed1[kN * 4];
__device__ float g_es2[kN];
__device__ float g_ed2[kN];
__device__ float g_phi[kN];                     // h2[n] . fcw
__device__ float g_c0;                          // b2 . fcw + fcb
__device__ __align__(16) float g_p1s[4 * 128];  // folded W1_h @ a1_src_h
__device__ __align__(16) float g_p1d[4 * 128];
// CSR by destination:
__device__ int g_deg[kN];
__device__ int g_ptr[kN + 1];
__device__ int g_cur[kN];
__device__ int g_srcs[kEt];
__device__ int g_bsum[kScanB];
__device__ int g_boff[kScanB];

__device__ __forceinline__ float lrelu(float x) { return x > 0.f ? x : kSlope * x; }

__device__ __forceinline__ bf8_t bf8_zero() {
  uint4 z = make_uint4(0u, 0u, 0u, 0u);
  return *(bf8_t*)&z;
}

// round-to-nearest-even f32 -> bf16
__device__ __forceinline__ unsigned short f2bf(float v, float& hi_f) {
  unsigned u = __float_as_uint(v);
  unsigned r = (u + 0x7FFFu + ((u >> 16) & 1u)) & 0xFFFF0000u;
  hi_f = __uint_as_float(r);
  return (unsigned short)(r >> 16);
}
__device__ __forceinline__ unsigned short f2bf1(float v) {
  float dummy;
  return f2bf(v, dummy);
}
__device__ __forceinline__ void split_bf(float v, unsigned short& h, unsigned short& l) {
  float hf, lf;
  h = f2bf(v, hf);
  l = f2bf(v - hf, lf);
}

// ------- merged init: zero(deg,es2,ed2,phi) | W1 conv | prep1 | U | c0 ------
__global__ __launch_bounds__(256) void k_init(const float* __restrict__ W1,
    const float* __restrict__ W2, const float* __restrict__ a1s,
    const float* __restrict__ a1d, const float* __restrict__ a2s,
    const float* __restrict__ a2d, const float* __restrict__ b2,
    const float* __restrict__ fcw, const float* __restrict__ fcb) {
  const int b = blockIdx.x, t = threadIdx.x;
  if (b < 197) {
    int i = b * 256 + t;
    if (i < kN) {
      g_deg[i] = 0;
      g_es2[i] = 0.f;
      g_ed2[i] = 0.f;
      g_phi[i] = 0.f;
    }
  } else if (b < 453) {
    int gid = (b - 197) * 256 + t;   // 0..65535 : W1 -> per-head W1^T hi/lo
    int h = gid >> 14, rem = gid & 16383;
    int c = rem >> 7, j = rem & 127;
    float v = W1[(size_t)c * 512 + h * 128 + j];
    unsigned short hh, ll;
    split_bf(v, hh, ll);
    size_t o = ((size_t)h * 128 + j) * 128 + c;
    g_w1t_h[o] = hh; g_w1t_l[o] = ll;
  } else if (b < 457) {
    int gid = (b - 453) * 256 + t;   // 0..1023 : fold a1 through W1
    int which = gid >> 9, idx = gid & 511;
    int h = idx >> 7, k = idx & 127;
    const float* a = which ? a1d : a1s;
    const float* wrow = W1 + (size_t)k * 512 + h * 128;
    float s = 0.f;
#pragma unroll 8
    for (int c = 0; c < 128; ++c) s += wrow[c] * a[h * 128 + c];
    (which ? g_p1d : g_p1s)[idx] = s;
  } else if (b < 463) {
    int gid = (b - 457) * 256 + t;   // 0..1535 : U[v][k] = W2[k,:] . V_v
    if (gid < 1536) {
      int v = gid >> 9, k = gid & 511;
      const float* vv = v == 0 ? a2s : v == 1 ? a2d : fcw;
      const float* wrow = W2 + (size_t)k * 128;
      float s = 0.f;
#pragma unroll 8
      for (int c = 0; c < 128; ++c) s += wrow[c] * vv[c];
      g_u[v][k] = s;
    }
  } else {
    if (t < 64) {
      float s = b2[t] * fcw[t] + b2[64 + t] * fcw[64 + t];
#pragma unroll
      for (int off = 32; off > 0; off >>= 1) s += __shfl_down(s, off);
      if (t == 0) g_c0 = s + fcb[0];
    }
  }
}

__global__ __launch_bounds__(256) void k_hist(const int* __restrict__ ei) {
  int e = blockIdx.x * 256 + threadIdx.x;
  if (e >= kEt) return;
  int d = (e < kE) ? ei[kE + e] : e - kE;
  atomicAdd(&g_deg[d], 1);
}

// ---- parallel scan, phase A: per-256-chunk LDS scan + block sums -----------
__global__ __launch_bounds__(256) void k_scanA() {
  __shared__ int s[256];
  const int b = blockIdx.x, t = threadIdx.x;
  const int i = b * 256 + t;
  int d = (i < kN) ? g_deg[i] : 0;
  s[t] = d;
  __syncthreads();
  for (int off = 1; off < 256; off <<= 1) {
    int v = s[t];
    int u = (t >= off) ? s[t - off] : 0;
    __syncthreads();
    s[t] = v + u;
    __syncthreads();
  }
  if (t == 255) g_bsum[b] = s[255];
  if (i < kN) g_ptr[i] = s[t] - d;   // local exclusive
}

// ---- phase B: single-block scan of 196 block sums -> exclusive offsets -----
__global__ __launch_bounds__(256) void k_scanB() {
  __shared__ int s[256];
  const int t = threadIdx.x;
  int v = (t < kScanB) ? g_bsum[t] : 0;
  s[t] = v;
  __syncthreads();
  for (int off = 1; off < 256; off <<= 1) {
    int a = s[t];
    int u = (t >= off) ? s[t - off] : 0;
    __syncthreads();
    s[t] = a + u;
    __syncthreads();
  }
  if (t < kScanB) g_boff[t] = s[t] - v;
  if (t == 0) g_ptr[kN] = kEt;
}

// ---- phase C: add block offsets, mirror into g_cur -------------------------
__global__ __launch_bounds__(256) void k_scanC() {
  const int b = blockIdx.x, t = threadIdx.x;
  const int i = b * 256 + t;
  if (i >= kN) return;
  int p = g_ptr[i] + g_boff[b];
  g_ptr[i] = p;
  g_cur[i] = p;
}

__global__ __launch_bounds__(256) void k_scatter(const int* __restrict__ ei) {
  int e = blockIdx.x * 256 + threadIdx.x;
  if (e >= kEt) return;
  int s, d;
  if (e < kE) { s = ei[e]; d = ei[kE + e]; } else { s = d = e - kE; }
  int slot = atomicAdd(&g_cur[d], 1);
  g_srcs[slot] = s;
}

// ---- layer-1 scores directly from x ----
__global__ __launch_bounds__(256) void k_scores1x(const float* __restrict__ x) {
  const int lane = threadIdx.x & 63;
  const int n = (blockIdx.x * 256 + threadIdx.x) >> 6;
  if (n >= kN) return;
  float x0 = x[(size_t)n * 128 + lane];
  float x1 = x[(size_t)n * 128 + 64 + lane];
  float s[4], d[4];
#pragma unroll
  for (int h = 0; h < 4; ++h) {
    s[h] = x0 * g_p1s[h * 128 + lane] + x1 * g_p1s[h * 128 + 64 + lane];
    d[h] = x0 * g_p1d[h * 128 + lane] + x1 * g_p1d[h * 128 + 64 + lane];
  }
#pragma unroll
  for (int off = 32; off > 0; off >>= 1) {
#pragma unroll
    for (int h = 0; h < 4; ++h) {
      s[h] += __shfl_down(s[h], off);
      d[h] += __shfl_down(d[h], off);
    }
  }
  if (lane == 0) {
    *(float4*)(g_es1 + (size_t)n * 4) = make_float4(s[0], s[1], s[2], s[3]);
    *(float4*)(g_ed1 + (size_t)n * 4) = make_float4(d[0], d[1], d[2], d[3]);
  }
}

// ---- layer-1 aggregation: 4 edges/iter (16-lane quarters), 2xfloat4/lane ---
// Emits single bf16 aggx (lo residual dropped — error budget analysis r18).
__global__ __launch_bounds__(256) void k_agg1x(const float* __restrict__ x) {
  const int lane = threadIdx.x & 63;
  const int n = (blockIdx.x * 256 + threadIdx.x) >> 6;
  if (n >= kN) return;
  const int beg = g_ptr[n], end = g_ptr[n + 1];
  const float4 ed = *(const float4*)(g_ed1 + (size_t)n * 4);
  const int qt = lane >> 4, ql = lane & 15;
  float z0 = 0.f, z1 = 0.f, z2 = 0.f, z3 = 0.f;
  float acc[4][8] = {};
  for (int base = beg; base < end; base += 64) {
    const int cnt = min(64, end - base);
    int s = 0;
    float w0 = 0.f, w1 = 0.f, w2 = 0.f, w3 = 0.f;
    if (lane < cnt) {
      s = g_srcs[base + lane];
      float4 es = *(const float4*)(g_es1 + (size_t)s * 4);
      w0 = __expf(lrelu(es.x + ed.x));
      w1 = __expf(lrelu(es.y + ed.y));
      w2 = __expf(lrelu(es.z + ed.z));
      w3 = __expf(lrelu(es.w + ed.w));
      z0 += w0; z1 += w1; z2 += w2; z3 += w3;
    }
    const int quads = (cnt + 3) >> 2;
#pragma unroll 2
    for (int p = 0; p < quads; ++p) {
      int ei = 4 * p + qt;
      int   sj = __shfl(s, ei);
      float b0 = __shfl(w0, ei), b1 = __shfl(w1, ei);
      float b2 = __shfl(w2, ei), b3 = __shfl(w3, ei);
      const float* xp = x + (size_t)sj * 128 + ql * 8;
      float4 f0 = *(const float4*)xp;
      float4 f1 = *(const float4*)(xp + 4);
      float fv[8] = {f0.x, f0.y, f0.z, f0.w, f1.x, f1.y, f1.z, f1.w};
#pragma unroll
      for (int k = 0; k < 8; ++k) {
        acc[0][k] += b0 * fv[k];
        acc[1][k] += b1 * fv[k];
        acc[2][k] += b2 * fv[k];
        acc[3][k] += b3 * fv[k];
      }
    }
  }
#pragma unroll
  for (int h = 0; h < 4; ++h)
#pragma unroll
    for (int k = 0; k < 8; ++k) {
      acc[h][k] += __shfl_xor(acc[h][k], 16);
      acc[h][k] += __shfl_xor(acc[h][k], 32);
    }
#pragma unroll
  for (int off = 1; off < 64; off <<= 1) {
    z0 += __shfl_xor(z0, off); z1 += __shfl_xor(z1, off);
    z2 += __shfl_xor(z2, off); z3 += __shfl_xor(z3, off);
  }
  float zh = qt == 0 ? z0 : qt == 1 ? z1 : qt == 2 ? z2 : z3;
  float iz = 1.f / zh;
  ushort4 o0, o1;
  float v[8];
#pragma unroll
  for (int k = 0; k < 8; ++k)
    v[k] = (qt == 0 ? acc[0][k] : qt == 1 ? acc[1][k] : qt == 2 ? acc[2][k] : acc[3][k]) * iz;
  o0.x = f2bf1(v[0]); o0.y = f2bf1(v[1]); o0.z = f2bf1(v[2]); o0.w = f2bf1(v[3]);
  o1.x = f2bf1(v[4]); o1.y = f2bf1(v[5]); o1.z = f2bf1(v[6]); o1.w = f2bf1(v[7]);
  size_t o = (size_t)n * 512 + qt * 128 + ql * 8;
  *(ushort4*)(g_aggx + o)     = o0;
  *(ushort4*)(g_aggx + o + 4) = o1;
}

// ------- fused layer-1 expand + layer-2 projections, head-split -------------
// Grid (1, 782, 4): blockIdx.z = head. Barrier-free MFMA h1 = aggx_h @ W1_h
// (A single-bf16, W split hi/lo -> 2 passes), relu+bias, dot with U columns,
// per-block reduce, atomicAdd into es2/ed2/phi (zeroed in k_init).
__global__ __launch_bounds__(256) void k_fused(const float* __restrict__ b1) {
  __shared__ float sred[2][64][3];
  const int t = threadIdx.x;
  const int lane = t & 63, w = t >> 6;
  const int wrow = w >> 1, wcol = w & 1;
  const int ln15 = lane & 15, q = lane >> 4, qo = q * 8;
  const int row0 = blockIdx.y * 64;
  const int h = blockIdx.z;

  float part[2][4][3] = {};      // [i][reg][v]
  f4_t h1acc[2][4] = {};
#pragma unroll
  for (int ks = 0; ks < 128; ks += 32) {
    bf8_t ah[2];
#pragma unroll
    for (int i = 0; i < 2; ++i) {
      int r = row0 + wrow * 32 + i * 16 + ln15;
      ah[i] = bf8_zero();
      if (r < kN)
        ah[i] = *(const bf8_t*)&g_aggx[(size_t)r * 512 + h * 128 + ks + qo];
    }
#pragma unroll
    for (int j = 0; j < 4; ++j) {
      size_t gb = ((size_t)h * 128 + wcol * 64 + j * 16 + ln15) * 128 + ks + qo;
      bf8_t bh = *(const bf8_t*)&g_w1t_h[gb];
      bf8_t bl = *(const bf8_t*)&g_w1t_l[gb];
#pragma unroll
      for (int i = 0; i < 2; ++i)
        h1acc[i][j] = __builtin_amdgcn_mfma_f32_16x16x32_bf16(ah[i], bh, h1acc[i][j], 0, 0, 0);
#pragma unroll
      for (int i = 0; i < 2; ++i)
        h1acc[i][j] = __builtin_amdgcn_mfma_f32_16x16x32_bf16(ah[i], bl, h1acc[i][j], 0, 0, 0);
    }
  }
  // epilogue: relu(h1+b1) dotted with U columns
#pragma unroll
  for (int j = 0; j < 4; ++j) {
    int col = h * 128 + wcol * 64 + j * 16 + ln15;
    float bv = b1[col];
    float u0 = g_u[0][col], u1 = g_u[1][col], u2 = g_u[2][col];
#pragma unroll
    for (int i = 0; i < 2; ++i)
#pragma unroll
      for (int reg = 0; reg < 4; ++reg) {
        float v = fmaxf(h1acc[i][j][reg] + bv, 0.f);
        part[i][reg][0] += v * u0;
        part[i][reg][1] += v * u1;
        part[i][reg][2] += v * u2;
      }
  }
  // reduce over the 16 lanes of each quad-group (same q)
#pragma unroll
  for (int off = 1; off < 16; off <<= 1)
#pragma unroll
    for (int i = 0; i < 2; ++i)
#pragma unroll
      for (int reg = 0; reg < 4; ++reg)
#pragma unroll
        for (int v = 0; v < 3; ++v)
          part[i][reg][v] += __shfl_xor(part[i][reg][v], off);
  if (ln15 == 0) {
#pragma unroll
    for (int i = 0; i < 2; ++i)
#pragma unroll
      for (int reg = 0; reg < 4; ++reg) {
        int rl = wrow * 32 + i * 16 + q * 4 + reg;
#pragma unroll
        for (int v = 0; v < 3; ++v) sred[wcol][rl][v] = part[i][reg][v];
      }
  }
  __syncthreads();
  if (t < 192) {
    int row = t / 3, v = t - row * 3;
    float s = sred[0][row][v] + sred[1][row][v];
    int r = row0 + row;
    if (r < kN)
      atomicAdd(&(v == 0 ? g_es2 : v == 1 ? g_ed2 : g_phi)[r], s);
  }
}

// ---- layer-2 scalar aggregation + output: out = (sum w*phi)/z + c0 ---------
__global__ __launch_bounds__(256) void k_agg2s(float* __restrict__ out) {
  const int lane = threadIdx.x & 63;
  const int n = (blockIdx.x * 256 + threadIdx.x) >> 6;
  if (n >= kN) return;
  const int beg = g_ptr[n], end = g_ptr[n + 1];
  const float ed = g_ed2[n];
  float zp = 0.f, num = 0.f;
  for (int base = beg; base < end; base += 64) {
    int slot = base + lane;
    if (slot < end) {
      int s = g_srcs[slot];
      float w = __expf(lrelu(g_es2[s] + ed));
      zp += w;
      num += w * g_phi[s];
    }
  }
#pragma unroll
  for (int off = 1; off < 64; off <<= 1) {
    zp  += __shfl_xor(zp, off);
    num += __shfl_xor(num, off);
  }
  if (lane == 0) out[n] = num / zp + g_c0;
}

extern "C" void kernel_launch(void* const* d_in, const int* in_sizes, int n_in,
                              void* d_out, int out_size, void* d_ws, size_t ws_size,
                              hipStream_t stream) {
  const float* x   = (const float*)d_in[0];
  const int*   ei  = (const int*)d_in[1];
  const float* W1  = (const float*)d_in[2];
  const float* a1s = (const float*)d_in[3];
  const float* a1d = (const float*)d_in[4];
  const float* b1  = (const float*)d_in[5];
  const float* W2  = (const float*)d_in[6];
  const float* a2s = (const float*)d_in[7];
  const float* a2d = (const float*)d_in[8];
  const float* b2  = (const float*)d_in[9];
  const float* fcw = (const float*)d_in[10];
  const float* fcb = (const float*)d_in[11];
  float* out = (float*)d_out;
  (void)d_ws; (void)ws_size; (void)in_sizes; (void)n_in; (void)out_size;

  // ---- init (zero | W1 conv | prep1 | U | c0) + CSR build ----
  k_init<<<464, 256, 0, stream>>>(W1, W2, a1s, a1d, a2s, a2d, b2, fcw, fcb);
  k_hist<<<(kEt + 255) / 256, 256, 0, stream>>>(ei);
  k_scanA<<<kScanB, 256, 0, stream>>>();
  k_scanB<<<1, 256, 0, stream>>>();
  k_scanC<<<kScanB, 256, 0, stream>>>();
  k_scatter<<<(kEt + 255) / 256, 256, 0, stream>>>(ei);

  // ---- layer 1 ----
  k_scores1x<<<(kN * 64 + 255) / 256, 256, 0, stream>>>(x);
  k_agg1x<<<(kN * 64 + 255) / 256, 256, 0, stream>>>(x);

  // ---- fused expand + layer-2 projections (head-split, atomic combine) ----
  dim3 gf(1, (kN + 63) / 64, 4);
  k_fused<<<gf, 256, 0, stream>>>(b1);

  // ---- layer-2 scalar edge aggregation + output ----
  k_agg2s<<<(kN * 64 + 255) / 256, 256, 0, stream>>>(out);
}

// Round 19
// 367.657 us; speedup vs baseline: 1.8638x; 1.0087x over previous
//
#include <hip/hip_runtime.h>
#include <cstdint>
#include <cstddef>

constexpr int kN   = 50000;          // nodes
constexpr int kE   = 800000;         // edges (without self loops)
constexpr int kEt  = kE + kN;        // edges + self loops
constexpr float kSlope = 0.2f;       // leaky relu slope
constexpr int kScanB = (kN + 255) / 256;   // 196 scan blocks
constexpr int kConvB = (kN * 16 + 255) / 256;  // x-conversion blocks (3125)

typedef __attribute__((ext_vector_type(8))) short bf8_t;   // 8 bf16 = 4 VGPRs
typedef __attribute__((ext_vector_type(4))) float f4_t;

// ---------------- static device workspace (d_ws unused) ---------------------
__device__ __align__(16) unsigned short g_xb[(size_t)kN * 128];     // x in bf16
__device__ __align__(16) unsigned short g_aggx[(size_t)kN * 512];   // agg of x, bf16
__device__ __align__(16) unsigned short g_w1t_h[4 * 128 * 128];     // W1^T per head, hi
__device__ __align__(16) unsigned short g_w1t_l[4 * 128 * 128];
__device__ __align__(16) float g_u[3][512];     // W2 @ [a2s, a2d, fcw]
__device__ __align__(16) float g_es1[kN * 4];
__device__ __align__(16) float g_ed1[kN * 4];
__device__ float g_es2[kN];
__device__ float g_ed2[kN];
__device__ float g_phi[kN];                     // h2[n] . fcw
__device__ float g_c0;                          // b2 . fcw + fcb
__device__ __align__(16) float g_p1s[4 * 128];  // folded W1_h @ a1_src_h
__device__ __align__(16) float g_p1d[4 * 128];
// CSR by destination:
__device__ int g_deg[kN];
__device__ int g_ptr[kN + 1];
__device__ int g_cur[kN];
__device__ int g_srcs[kEt];
__device__ int g_bsum[kScanB];
__device__ int g_boff[kScanB];

__device__ __forceinline__ float lrelu(float x) { return x > 0.f ? x : kSlope * x; }

__device__ __forceinline__ bf8_t bf8_zero() {
  uint4 z = make_uint4(0u, 0u, 0u, 0u);
  return *(bf8_t*)&z;
}

// round-to-nearest-even f32 -> bf16
__device__ __forceinline__ unsigned short f2bf(float v, float& hi_f) {
  unsigned u = __float_as_uint(v);
  unsigned r = (u + 0x7FFFu + ((u >> 16) & 1u)) & 0xFFFF0000u;
  hi_f = __uint_as_float(r);
  return (unsigned short)(r >> 16);
}
__device__ __forceinline__ unsigned short f2bf1(float v) {
  float dummy;
  return f2bf(v, dummy);
}
__device__ __forceinline__ void split_bf(float v, unsigned short& h, unsigned short& l) {
  float hf, lf;
  h = f2bf(v, hf);
  l = f2bf(v - hf, lf);
}

// ------- merged init: zero | W1 conv | prep1 | U | c0 | x->bf16 -------------
__global__ __launch_bounds__(256) void k_init(const float* __restrict__ x,
    const float* __restrict__ W1, const float* __restrict__ W2,
    const float* __restrict__ a1s, const float* __restrict__ a1d,
    const float* __restrict__ a2s, const float* __restrict__ a2d,
    const float* __restrict__ b2, const float* __restrict__ fcw,
    const float* __restrict__ fcb) {
  const int b = blockIdx.x, t = threadIdx.x;
  if (b < 197) {
    int i = b * 256 + t;
    if (i < kN) {
      g_deg[i] = 0;
      g_es2[i] = 0.f;
      g_ed2[i] = 0.f;
      g_phi[i] = 0.f;
    }
  } else if (b < 453) {
    int gid = (b - 197) * 256 + t;   // 0..65535 : W1 -> per-head W1^T hi/lo
    int h = gid >> 14, rem = gid & 16383;
    int c = rem >> 7, j = rem & 127;
    float v = W1[(size_t)c * 512 + h * 128 + j];
    unsigned short hh, ll;
    split_bf(v, hh, ll);
    size_t o = ((size_t)h * 128 + j) * 128 + c;
    g_w1t_h[o] = hh; g_w1t_l[o] = ll;
  } else if (b < 457) {
    int gid = (b - 453) * 256 + t;   // 0..1023 : fold a1 through W1
    int which = gid >> 9, idx = gid & 511;
    int h = idx >> 7, k = idx & 127;
    const float* a = which ? a1d : a1s;
    const float* wrow = W1 + (size_t)k * 512 + h * 128;
    float s = 0.f;
#pragma unroll 8
    for (int c = 0; c < 128; ++c) s += wrow[c] * a[h * 128 + c];
    (which ? g_p1d : g_p1s)[idx] = s;
  } else if (b < 463) {
    int gid = (b - 457) * 256 + t;   // 0..1535 : U[v][k] = W2[k,:] . V_v
    if (gid < 1536) {
      int v = gid >> 9, k = gid & 511;
      const float* vv = v == 0 ? a2s : v == 1 ? a2d : fcw;
      const float* wrow = W2 + (size_t)k * 128;
      float s = 0.f;
#pragma unroll 8
      for (int c = 0; c < 128; ++c) s += wrow[c] * vv[c];
      g_u[v][k] = s;
    }
  } else if (b < 464) {
    if (t < 64) {
      float s = b2[t] * fcw[t] + b2[64 + t] * fcw[64 + t];
#pragma unroll
      for (int off = 32; off > 0; off >>= 1) s += __shfl_down(s, off);
      if (t == 0) g_c0 = s + fcb[0];
    }
  } else {
    // x -> bf16, 8 elems per thread
    int g = (b - 464) * 256 + t;
    if (g < kN * 16) {
      const float* xp = x + (size_t)g * 8;
      float4 f0 = *(const float4*)xp;
      float4 f1 = *(const float4*)(xp + 4);
      unsigned w0 = (unsigned)f2bf1(f0.x) | ((unsigned)f2bf1(f0.y) << 16);
      unsigned w1 = (unsigned)f2bf1(f0.z) | ((unsigned)f2bf1(f0.w) << 16);
      unsigned w2 = (unsigned)f2bf1(f1.x) | ((unsigned)f2bf1(f1.y) << 16);
      unsigned w3 = (unsigned)f2bf1(f1.z) | ((unsigned)f2bf1(f1.w) << 16);
      *(uint4*)(g_xb + (size_t)g * 8) = make_uint4(w0, w1, w2, w3);
    }
  }
}

__global__ __launch_bounds__(256) void k_hist(const int* __restrict__ ei) {
  int e = blockIdx.x * 256 + threadIdx.x;
  if (e >= kEt) return;
  int d = (e < kE) ? ei[kE + e] : e - kE;
  atomicAdd(&g_deg[d], 1);
}

// ---- parallel scan, phase A: per-256-chunk LDS scan + block sums -----------
__global__ __launch_bounds__(256) void k_scanA() {
  __shared__ int s[256];
  const int b = blockIdx.x, t = threadIdx.x;
  const int i = b * 256 + t;
  int d = (i < kN) ? g_deg[i] : 0;
  s[t] = d;
  __syncthreads();
  for (int off = 1; off < 256; off <<= 1) {
    int v = s[t];
    int u = (t >= off) ? s[t - off] : 0;
    __syncthreads();
    s[t] = v + u;
    __syncthreads();
  }
  if (t == 255) g_bsum[b] = s[255];
  if (i < kN) g_ptr[i] = s[t] - d;   // local exclusive
}

// ---- phase B: single-block scan of 196 block sums -> exclusive offsets -----
__global__ __launch_bounds__(256) void k_scanB() {
  __shared__ int s[256];
  const int t = threadIdx.x;
  int v = (t < kScanB) ? g_bsum[t] : 0;
  s[t] = v;
  __syncthreads();
  for (int off = 1; off < 256; off <<= 1) {
    int a = s[t];
    int u = (t >= off) ? s[t - off] : 0;
    __syncthreads();
    s[t] = a + u;
    __syncthreads();
  }
  if (t < kScanB) g_boff[t] = s[t] - v;
  if (t == 0) g_ptr[kN] = kEt;
}

// ---- phase C: add block offsets, mirror into g_cur -------------------------
__global__ __launch_bounds__(256) void k_scanC() {
  const int b = blockIdx.x, t = threadIdx.x;
  const int i = b * 256 + t;
  if (i >= kN) return;
  int p = g_ptr[i] + g_boff[b];
  g_ptr[i] = p;
  g_cur[i] = p;
}

__global__ __launch_bounds__(256) void k_scatter(const int* __restrict__ ei) {
  int e = blockIdx.x * 256 + threadIdx.x;
  if (e >= kEt) return;
  int s, d;
  if (e < kE) { s = ei[e]; d = ei[kE + e]; } else { s = d = e - kE; }
  int slot = atomicAdd(&g_cur[d], 1);
  g_srcs[slot] = s;
}

// ---- layer-1 scores directly from x ----
__global__ __launch_bounds__(256) void k_scores1x(const float* __restrict__ x) {
  const int lane = threadIdx.x & 63;
  const int n = (blockIdx.x * 256 + threadIdx.x) >> 6;
  if (n >= kN) return;
  float x0 = x[(size_t)n * 128 + lane];
  float x1 = x[(size_t)n * 128 + 64 + lane];
  float s[4], d[4];
#pragma unroll
  for (int h = 0; h < 4; ++h) {
    s[h] = x0 * g_p1s[h * 128 + lane] + x1 * g_p1s[h * 128 + 64 + lane];
    d[h] = x0 * g_p1d[h * 128 + lane] + x1 * g_p1d[h * 128 + 64 + lane];
  }
#pragma unroll
  for (int off = 32; off > 0; off >>= 1) {
#pragma unroll
    for (int h = 0; h < 4; ++h) {
      s[h] += __shfl_down(s[h], off);
      d[h] += __shfl_down(d[h], off);
    }
  }
  if (lane == 0) {
    *(float4*)(g_es1 + (size_t)n * 4) = make_float4(s[0], s[1], s[2], s[3]);
    *(float4*)(g_ed1 + (size_t)n * 4) = make_float4(d[0], d[1], d[2], d[3]);
  }
}

// ---- layer-1 aggregation: 4 edges/iter (16-lane quarters), bf16 x gathers --
__global__ __launch_bounds__(256) void k_agg1x() {
  const int lane = threadIdx.x & 63;
  const int n = (blockIdx.x * 256 + threadIdx.x) >> 6;
  if (n >= kN) return;
  const int beg = g_ptr[n], end = g_ptr[n + 1];
  const float4 ed = *(const float4*)(g_ed1 + (size_t)n * 4);
  const int qt = lane >> 4, ql = lane & 15;
  float z0 = 0.f, z1 = 0.f, z2 = 0.f, z3 = 0.f;
  float acc[4][8] = {};
  for (int base = beg; base < end; base += 64) {
    const int cnt = min(64, end - base);
    int s = 0;
    float w0 = 0.f, w1 = 0.f, w2 = 0.f, w3 = 0.f;
    if (lane < cnt) {
      s = g_srcs[base + lane];
      float4 es = *(const float4*)(g_es1 + (size_t)s * 4);
      w0 = __expf(lrelu(es.x + ed.x));
      w1 = __expf(lrelu(es.y + ed.y));
      w2 = __expf(lrelu(es.z + ed.z));
      w3 = __expf(lrelu(es.w + ed.w));
      z0 += w0; z1 += w1; z2 += w2; z3 += w3;
    }
    const int quads = (cnt + 3) >> 2;
#pragma unroll 2
    for (int p = 0; p < quads; ++p) {
      int ei = 4 * p + qt;
      int   sj = __shfl(s, ei);
      float b0 = __shfl(w0, ei), b1 = __shfl(w1, ei);
      float b2 = __shfl(w2, ei), b3 = __shfl(w3, ei);
      uint4 uu = *(const uint4*)(g_xb + (size_t)sj * 128 + ql * 8);
      unsigned ww[4] = {uu.x, uu.y, uu.z, uu.w};
      float fv[8];
#pragma unroll
      for (int wdi = 0; wdi < 4; ++wdi) {
        fv[2 * wdi]     = __uint_as_float(ww[wdi] << 16);
        fv[2 * wdi + 1] = __uint_as_float(ww[wdi] & 0xFFFF0000u);
      }
#pragma unroll
      for (int k = 0; k < 8; ++k) {
        acc[0][k] += b0 * fv[k];
        acc[1][k] += b1 * fv[k];
        acc[2][k] += b2 * fv[k];
        acc[3][k] += b3 * fv[k];
      }
    }
  }
#pragma unroll
  for (int h = 0; h < 4; ++h)
#pragma unroll
    for (int k = 0; k < 8; ++k) {
      acc[h][k] += __shfl_xor(acc[h][k], 16);
      acc[h][k] += __shfl_xor(acc[h][k], 32);
    }
#pragma unroll
  for (int off = 1; off < 64; off <<= 1) {
    z0 += __shfl_xor(z0, off); z1 += __shfl_xor(z1, off);
    z2 += __shfl_xor(z2, off); z3 += __shfl_xor(z3, off);
  }
  float zh = qt == 0 ? z0 : qt == 1 ? z1 : qt == 2 ? z2 : z3;
  float iz = 1.f / zh;
  ushort4 o0, o1;
  float v[8];
#pragma unroll
  for (int k = 0; k < 8; ++k)
    v[k] = (qt == 0 ? acc[0][k] : qt == 1 ? acc[1][k] : qt == 2 ? acc[2][k] : acc[3][k]) * iz;
  o0.x = f2bf1(v[0]); o0.y = f2bf1(v[1]); o0.z = f2bf1(v[2]); o0.w = f2bf1(v[3]);
  o1.x = f2bf1(v[4]); o1.y = f2bf1(v[5]); o1.z = f2bf1(v[6]); o1.w = f2bf1(v[7]);
  size_t o = (size_t)n * 512 + qt * 128 + ql * 8;
  *(ushort4*)(g_aggx + o)     = o0;
  *(ushort4*)(g_aggx + o + 4) = o1;
}

// ------- fused layer-1 expand + layer-2 projections, head-split -------------
__global__ __launch_bounds__(256) void k_fused(const float* __restrict__ b1) {
  __shared__ float sred[2][64][3];
  const int t = threadIdx.x;
  const int lane = t & 63, w = t >> 6;
  const int wrow = w >> 1, wcol = w & 1;
  const int ln15 = lane & 15, q = lane >> 4, qo = q * 8;
  const int row0 = blockIdx.y * 64;
  const int h = blockIdx.z;

  float part[2][4][3] = {};      // [i][reg][v]
  f4_t h1acc[2][4] = {};
#pragma unroll
  for (int ks = 0; ks < 128; ks += 32) {
    bf8_t ah[2];
#pragma unroll
    for (int i = 0; i < 2; ++i) {
      int r = row0 + wrow * 32 + i * 16 + ln15;
      ah[i] = bf8_zero();
      if (r < kN)
        ah[i] = *(const bf8_t*)&g_aggx[(size_t)r * 512 + h * 128 + ks + qo];
    }
#pragma unroll
    for (int j = 0; j < 4; ++j) {
      size_t gb = ((size_t)h * 128 + wcol * 64 + j * 16 + ln15) * 128 + ks + qo;
      bf8_t bh = *(const bf8_t*)&g_w1t_h[gb];
      bf8_t bl = *(const bf8_t*)&g_w1t_l[gb];
#pragma unroll
      for (int i = 0; i < 2; ++i)
        h1acc[i][j] = __builtin_amdgcn_mfma_f32_16x16x32_bf16(ah[i], bh, h1acc[i][j], 0, 0, 0);
#pragma unroll
      for (int i = 0; i < 2; ++i)
        h1acc[i][j] = __builtin_amdgcn_mfma_f32_16x16x32_bf16(ah[i], bl, h1acc[i][j], 0, 0, 0);
    }
  }
  // epilogue: relu(h1+b1) dotted with U columns
#pragma unroll
  for (int j = 0; j < 4; ++j) {
    int col = h * 128 + wcol * 64 + j * 16 + ln15;
    float bv = b1[col];
    float u0 = g_u[0][col], u1 = g_u[1][col], u2 = g_u[2][col];
#pragma unroll
    for (int i = 0; i < 2; ++i)
#pragma unroll
      for (int reg = 0; reg < 4; ++reg) {
        float v = fmaxf(h1acc[i][j][reg] + bv, 0.f);
        part[i][reg][0] += v * u0;
        part[i][reg][1] += v * u1;
        part[i][reg][2] += v * u2;
      }
  }
  // reduce over the 16 lanes of each quad-group (same q)
#pragma unroll
  for (int off = 1; off < 16; off <<= 1)
#pragma unroll
    for (int i = 0; i < 2; ++i)
#pragma unroll
      for (int reg = 0; reg < 4; ++reg)
#pragma unroll
        for (int v = 0; v < 3; ++v)
          part[i][reg][v] += __shfl_xor(part[i][reg][v], off);
  if (ln15 == 0) {
#pragma unroll
    for (int i = 0; i < 2; ++i)
#pragma unroll
      for (int reg = 0; reg < 4; ++reg) {
        int rl = wrow * 32 + i * 16 + q * 4 + reg;
#pragma unroll
        for (int v = 0; v < 3; ++v) sred[wcol][rl][v] = part[i][reg][v];
      }
  }
  __syncthreads();
  if (t < 192) {
    int row = t / 3, v = t - row * 3;
    float s = sred[0][row][v] + sred[1][row][v];
    int r = row0 + row;
    if (r < kN)
      atomicAdd(&(v == 0 ? g_es2 : v == 1 ? g_ed2 : g_phi)[r], s);
  }
}

// ---- layer-2 scalar aggregation + output: out = (sum w*phi)/z + c0 ---------
__global__ __launch_bounds__(256) void k_agg2s(float* __restrict__ out) {
  const int lane = threadIdx.x & 63;
  const int n = (blockIdx.x * 256 + threadIdx.x) >> 6;
  if (n >= kN) return;
  const int beg = g_ptr[n], end = g_ptr[n + 1];
  const float ed = g_ed2[n];
  float zp = 0.f, num = 0.f;
  for (int base = beg; base < end; base += 64) {
    int slot = base + lane;
    if (slot < end) {
      int s = g_srcs[slot];
      float w = __expf(lrelu(g_es2[s] + ed));
      zp += w;
      num += w * g_phi[s];
    }
  }
#pragma unroll
  for (int off = 1; off < 64; off <<= 1) {
    zp  += __shfl_xor(zp, off);
    num += __shfl_xor(num, off);
  }
  if (lane == 0) out[n] = num / zp + g_c0;
}

extern "C" void kernel_launch(void* const* d_in, const int* in_sizes, int n_in,
                              void* d_out, int out_size, void* d_ws, size_t ws_size,
                              hipStream_t stream) {
  const float* x   = (const float*)d_in[0];
  const int*   ei  = (const int*)d_in[1];
  const float* W1  = (const float*)d_in[2];
  const float* a1s = (const float*)d_in[3];
  const float* a1d = (const float*)d_in[4];
  const float* b1  = (const float*)d_in[5];
  const float* W2  = (const float*)d_in[6];
  const float* a2s = (const float*)d_in[7];
  const float* a2d = (const float*)d_in[8];
  const float* b2  = (const float*)d_in[9];
  const float* fcw = (const float*)d_in[10];
  const float* fcb = (const float*)d_in[11];
  float* out = (float*)d_out;
  (void)d_ws; (void)ws_size; (void)in_sizes; (void)n_in; (void)out_size;

  // ---- init (zero | W1 conv | prep1 | U | c0 | x->bf16) + CSR build ----
  k_init<<<464 + kConvB, 256, 0, stream>>>(x, W1, W2, a1s, a1d, a2s, a2d, b2, fcw, fcb);
  k_hist<<<(kEt + 255) / 256, 256, 0, stream>>>(ei);
  k_scanA<<<kScanB, 256, 0, stream>>>();
  k_scanB<<<1, 256, 0, stream>>>();
  k_scanC<<<kScanB, 256, 0, stream>>>();
  k_scatter<<<(kEt + 255) / 256, 256, 0, stream>>>(ei);

  // ---- layer 1 ----
  k_scores1x<<<(kN * 64 + 255) / 256, 256, 0, stream>>>(x);
  k_agg1x<<<(kN * 64 + 255) / 256, 256, 0, stream>>>();

  // ---- fused expand + layer-2 projections (head-split, atomic combine) ----
  dim3 gf(1, (kN + 63) / 64, 4);
  k_fused<<<gf, 256, 0, stream>>>(b1);

  // ---- layer-2 scalar edge aggregation + output ----
  k_agg2s<<<(kN * 64 + 255) / 256, 256, 0, stream>>>(out);
}